// Round 7
// baseline (9147.712 us; speedup 1.0000x reference)
//
#include <hip/hip_runtime.h>
#include <hip/hip_fp16.h>

// ---------------------------------------------------------------------------
// BernNet forward: x@W1+b1 -> relu -> 2x BernConv(K=10) -> h@W2+b2
// The 22 Chebyshev propagation passes are feature-column independent, so the
// 128 features are split into 8 chunks of 16, chunk c pinned to XCD c via
// blockIdx%8. Per-chunk fp16 gather mirror = (n+1)*32B = 3.2MB -> L2-resident
// per XCD. Mirrors store u = dinv[v]*T[v] (pre-scaled), so edges need no
// weight: CSR is a bare 4B col array; epilogue scales agg by -0.5*dinv[v].
// f32 recurrence masters stay in h-domain (chunk-major). Streaming traffic
// (col, f32 state) uses nontemporal hints (on clang ext_vector types -- the
// builtin rejects HIP_vector_type classes). Gather trip counts are
// wave-uniform; padding slots index dummy zero row n.
// ---------------------------------------------------------------------------

#define SCAN_BLOCK 256
#define SCAN_ITEMS 4
#define SCAN_CHUNK 1024

typedef float fx2 __attribute__((ext_vector_type(2)));

union fh2 { float f; __half2 h; };
union f2h4 { fx2 f2; __half2 h2[2]; };

__global__ __launch_bounds__(256) void hist_kernel(const int* __restrict__ src,
                                                   const int* __restrict__ dst,
                                                   int* __restrict__ deg_src,
                                                   int* __restrict__ cnt_dst, int E) {
    int stride = gridDim.x * blockDim.x;
    for (int e = blockIdx.x * blockDim.x + threadIdx.x; e < E; e += stride) {
        atomicAdd(&deg_src[src[e]], 1);
        atomicAdd(&cnt_dst[dst[e]], 1);
    }
}

__global__ __launch_bounds__(256) void dinv_kernel(const int* __restrict__ deg,
                                                   float* __restrict__ dinv, int n) {
    int i = blockIdx.x * blockDim.x + threadIdx.x;
    if (i < n) {
        int d = deg[i];
        dinv[i] = d > 0 ? rsqrtf((float)d) : 0.f;
    }
}

__global__ __launch_bounds__(SCAN_BLOCK) void scan_chunk_sum(const int* __restrict__ cnt,
                                                             int* __restrict__ bsum, int n) {
    __shared__ int sdata[SCAN_BLOCK];
    int tid = threadIdx.x;
    int base = blockIdx.x * SCAN_CHUNK + tid * SCAN_ITEMS;
    int s = 0;
    for (int i = 0; i < SCAN_ITEMS; ++i) {
        int idx = base + i;
        if (idx < n) s += cnt[idx];
    }
    sdata[tid] = s;
    __syncthreads();
    for (int off = SCAN_BLOCK / 2; off > 0; off >>= 1) {
        if (tid < off) sdata[tid] += sdata[tid + off];
        __syncthreads();
    }
    if (tid == 0) bsum[blockIdx.x] = sdata[0];
}

__global__ void scan_bsum(int* __restrict__ bsum, int nb) {
    if (threadIdx.x == 0 && blockIdx.x == 0) {
        int run = 0;
        for (int i = 0; i < nb; ++i) {
            int v = bsum[i];
            bsum[i] = run;
            run += v;
        }
    }
}

__global__ __launch_bounds__(SCAN_BLOCK) void scan_write(const int* __restrict__ cnt,
                                                         const int* __restrict__ bsum,
                                                         int* __restrict__ rowptr,
                                                         int* __restrict__ cursor,
                                                         int n, int total) {
    __shared__ int sdata[SCAN_BLOCK];
    int tid = threadIdx.x;
    int base = blockIdx.x * SCAN_CHUNK + tid * SCAN_ITEMS;
    int vals[SCAN_ITEMS];
    int s = 0;
    for (int i = 0; i < SCAN_ITEMS; ++i) {
        int idx = base + i;
        vals[i] = (idx < n) ? cnt[idx] : 0;
        s += vals[i];
    }
    sdata[tid] = s;
    __syncthreads();
    for (int off = 1; off < SCAN_BLOCK; off <<= 1) {
        int add = (tid >= off) ? sdata[tid - off] : 0;
        __syncthreads();
        sdata[tid] += add;
        __syncthreads();
    }
    int run = bsum[blockIdx.x] + sdata[tid] - s;
    for (int i = 0; i < SCAN_ITEMS; ++i) {
        int idx = base + i;
        if (idx < n) {
            rowptr[idx] = run;
            cursor[idx] = run;
        }
        run += vals[i];
    }
    if (blockIdx.x == 0 && tid == 0) rowptr[n] = total;
}

// bare 4B record per edge: source index only (weights folded into mirror)
__global__ __launch_bounds__(256) void scatter_kernel(const int* __restrict__ src,
                                                      const int* __restrict__ dst,
                                                      int* __restrict__ cursor,
                                                      int* __restrict__ col, int E) {
    int stride = gridDim.x * blockDim.x;
    for (int e = blockIdx.x * blockDim.x + threadIdx.x; e < E; e += stride) {
        int d = dst[e];
        int p = atomicAdd(&cursor[d], 1);
        col[p] = src[e];
    }
}

// f32 chunk-major -> pre-scaled fp16 mirror (u = dinv[v] * h[v])
// grid: (x: strided over n*4 float4s, y: chunk 0..7)
__global__ __launch_bounds__(256) void mirror_kernel(const float4* __restrict__ src,
                                                     fx2* __restrict__ dst,
                                                     const float* __restrict__ dinv,
                                                     int n) {
    int c = blockIdx.y;
    size_t cs4 = (size_t)n * 4;         // float4 per f32 chunk
    size_t csm = (size_t)(n + 1) * 4;   // fx2 per mirror chunk
    int stride = gridDim.x * blockDim.x;
    for (int i = blockIdx.x * blockDim.x + threadIdx.x; i < n * 4; i += stride) {
        int v = i >> 2;
        float dv = dinv[v];
        float4 x = src[cs4 * c + i];
        f2h4 u;
        u.h2[0] = __floats2half2_rn(x.x * dv, x.y * dv);
        u.h2[1] = __floats2half2_rn(x.z * dv, x.w * dv);
        dst[csm * c + i] = u.f2;
    }
}

// zero the dummy gather row (index n) of both mirrors
__global__ void pad_kernel(float* __restrict__ mA, float* __restrict__ mB, int n) {
    int t = threadIdx.x;  // 128 threads
    size_t csh = (size_t)(n + 1) * 8;   // dwords per mirror chunk
    int c = (t >> 3) & 7;
    int fl = t & 7;
    if (t < 64) mA[csh * c + (size_t)n * 8 + fl] = 0.f;
    else if (t < 128) mB[csh * c + (size_t)n * 8 + fl] = 0.f;
}

// -------------------- GEMM1: h = relu(x @ W1 + b1) -> chunk-major ----------
#define G1_ROWS 16
__global__ __launch_bounds__(128) void gemm1_kernel(const float* __restrict__ X,
                                                    const float* __restrict__ W,
                                                    const float* __restrict__ b,
                                                    float* __restrict__ H, int n) {
    __shared__ float xt[G1_ROWS][256];
    int j = threadIdx.x;  // output column 0..127
    int r0 = blockIdx.x * G1_ROWS;
    for (int i = threadIdx.x; i < G1_ROWS * 256; i += 128) {
        int r = i >> 8, k = i & 255;
        int row = r0 + r;
        xt[r][k] = (row < n) ? X[(size_t)row * 256 + k] : 0.f;
    }
    __syncthreads();
    float acc[G1_ROWS];
#pragma unroll
    for (int r = 0; r < G1_ROWS; ++r) acc[r] = 0.f;
    for (int k = 0; k < 256; ++k) {
        float wk = W[k * 128 + j];
#pragma unroll
        for (int r = 0; r < G1_ROWS; ++r) acc[r] += xt[r][k] * wk;
    }
    float bj = b[j];
    size_t cs32 = (size_t)n * 16;
    size_t cbase = (size_t)(j >> 4) * cs32 + (j & 15);
    for (int r = 0; r < G1_ROWS; ++r) {
        int row = r0 + r;
        if (row < n) H[cbase + (size_t)row * 16] = fmaxf(acc[r] + bj, 0.f);
    }
}

// -------------------- GEMM2: out = h(chunk-major) @ W2 + b2 ----------------
#define G2_ROWS 32
__global__ __launch_bounds__(64) void gemm2_kernel(const float* __restrict__ H,
                                                   const float* __restrict__ W,
                                                   const float* __restrict__ b,
                                                   float* __restrict__ O, int n) {
    __shared__ float xt[G2_ROWS][128];
    int j = threadIdx.x;  // output column 0..63
    int r0 = blockIdx.x * G2_ROWS;
    size_t cs32 = (size_t)n * 16;
    for (int i = threadIdx.x; i < G2_ROWS * 128; i += 64) {
        int r = i >> 7, k = i & 127;
        int row = r0 + r;
        xt[r][k] = (row < n)
            ? H[(size_t)(k >> 4) * cs32 + (size_t)row * 16 + (k & 15)] : 0.f;
    }
    __syncthreads();
    float acc[G2_ROWS];
#pragma unroll
    for (int r = 0; r < G2_ROWS; ++r) acc[r] = 0.f;
    for (int k = 0; k < 128; ++k) {
        float wk = W[k * 64 + j];
#pragma unroll
        for (int r = 0; r < G2_ROWS; ++r) acc[r] += xt[r][k] * wk;
    }
    float bj = b[j];
    for (int r = 0; r < G2_ROWS; ++r) {
        int row = r0 + r;
        if (row < n) O[(size_t)row * 64 + j] = acc[r] + bj;
    }
}

// -------------------- Fused Chebyshev propagation step (chunked) -----------
// blockIdx.x & 7 = feature chunk (-> XCD); one node per wave (4 waves/block).
// Lanes: es = lane>>3 (edge slot), fl = lane&7 (feature dword: 2 fp16).
// Gather: 8 edges/iter; per lane one 4B mirror load; butterfly-reduce over
// es groups. Padding slots read dummy row n (zeros). agg = -0.5*dinv[v]*sum.
// mode 0: tx1 = 0.5x - agg -> TX1 (+MH); OUT = c0*x + c1*tx1
// mode 1: tx2 = x - 2*agg - t0; OUT += ck*tx2; T0 <- tx2 (+MH)
// mode 2: T0 <- relu(OUT + ck*tx2) (+MH)   (layer end)
// MH rows store u = dinv[v]*value (pre-scaled for the next gather).
__global__ __launch_bounds__(256) void prop_kernel(const float* __restrict__ XF,
                                                   const float* __restrict__ XH,
                                                   float* __restrict__ T0,
                                                   float* __restrict__ OUT,
                                                   float* __restrict__ TX1,
                                                   float* __restrict__ MH,
                                                   const int* __restrict__ rowptr,
                                                   const int* __restrict__ col,
                                                   const float* __restrict__ dinv,
                                                   const float* __restrict__ coeffs,
                                                   int cidx, int mode, int n) {
    int c = blockIdx.x & 7;
    int nb = blockIdx.x >> 3;
    int wid = threadIdx.x >> 6;
    int v = nb * 4 + wid;
    if (v >= n) return;
    int lane = threadIdx.x & 63;
    int es = lane >> 3;
    int fl = lane & 7;

    size_t csh = (size_t)(n + 1) * 8;  // dwords per mirror chunk
    const float* __restrict__ M = XH + csh * c;

    int start = rowptr[v];
    int end = rowptr[v + 1];
    float2 a0 = {0.f, 0.f}, a1 = {0.f, 0.f};

    for (int e0 = start; e0 < end; e0 += 64) {
        int m = end - e0;
        if (m > 64) m = 64;
        int colv = n;  // dummy zero row for padding slots
        if (lane < m) colv = __builtin_nontemporal_load(col + e0 + lane);
        int iters = (m + 7) >> 3;  // wave-uniform
        for (int t = 0; t < iters; t += 2) {
            int s0 = __shfl(colv, t * 8 + es);
            fh2 u0;
            u0.f = M[(size_t)s0 * 8 + fl];
            float2 x0 = __half22float2(u0.h);
            a0.x += x0.x;
            a0.y += x0.y;
            if (t + 1 < iters) {
                int s1 = __shfl(colv, t * 8 + 8 + es);
                fh2 u1;
                u1.f = M[(size_t)s1 * 8 + fl];
                float2 x1 = __half22float2(u1.h);
                a1.x += x1.x;
                a1.y += x1.y;
            }
        }
    }
    float2 acc;
    acc.x = a0.x + a1.x;
    acc.y = a0.y + a1.y;
    acc.x += __shfl_xor(acc.x, 8);
    acc.y += __shfl_xor(acc.y, 8);
    acc.x += __shfl_xor(acc.x, 16);
    acc.y += __shfl_xor(acc.y, 16);
    acc.x += __shfl_xor(acc.x, 32);
    acc.y += __shfl_xor(acc.y, 32);

    if (lane >= 8) return;  // lanes 0..7 hold agg for features (2*fl, 2*fl+1)

    float dv = dinv[v];
    float sw = -0.5f * dv;
    float gx = sw * acc.x;
    float gy = sw * acc.y;

    size_t i2 = (size_t)c * n * 8 + (size_t)v * 8 + fl;  // fx2 index
    const fx2* X2 = reinterpret_cast<const fx2*>(XF);
    fx2 self = __builtin_nontemporal_load(X2 + i2);
    fx2 wr;

    if (mode == 0) {
        float c0 = coeffs[cidx];
        float c1 = coeffs[cidx + 1];
        wr.x = 0.5f * self.x - gx;
        wr.y = 0.5f * self.y - gy;
        __builtin_nontemporal_store(wr, reinterpret_cast<fx2*>(TX1) + i2);
        fx2 o;
        o.x = c0 * self.x + c1 * wr.x;
        o.y = c0 * self.y + c1 * wr.y;
        __builtin_nontemporal_store(o, reinterpret_cast<fx2*>(OUT) + i2);
    } else {
        float ck = coeffs[cidx];
        fx2 t0v = __builtin_nontemporal_load(reinterpret_cast<const fx2*>(T0) + i2);
        fx2 t2;
        t2.x = self.x - 2.f * gx - t0v.x;
        t2.y = self.y - 2.f * gy - t0v.y;
        fx2 o = __builtin_nontemporal_load(reinterpret_cast<const fx2*>(OUT) + i2);
        o.x += ck * t2.x;
        o.y += ck * t2.y;
        if (mode == 1) {
            wr = t2;
            __builtin_nontemporal_store(wr, reinterpret_cast<fx2*>(T0) + i2);
            __builtin_nontemporal_store(o, reinterpret_cast<fx2*>(OUT) + i2);
        } else {
            wr.x = fmaxf(o.x, 0.f);
            wr.y = fmaxf(o.y, 0.f);
            __builtin_nontemporal_store(wr, reinterpret_cast<fx2*>(T0) + i2);
        }
    }
    if (MH) {
        fh2 u;
        u.h = __floats2half2_rn(wr.x * dv, wr.y * dv);
        MH[csh * c + (size_t)v * 8 + fl] = u.f;
    }
}

// ---------------------------------------------------------------------------

extern "C" void kernel_launch(void* const* d_in, const int* in_sizes, int n_in,
                              void* d_out, int out_size, void* d_ws, size_t ws_size,
                              hipStream_t stream) {
    const float* x      = (const float*)d_in[0];
    const int*   ei     = (const int*)d_in[1];
    const float* W1     = (const float*)d_in[2];
    const float* b1     = (const float*)d_in[3];
    const float* coeffs = (const float*)d_in[4];
    const float* W2     = (const float*)d_in[5];
    const float* b2     = (const float*)d_in[6];
    float* out = (float*)d_out;

    const int n = in_sizes[0] / 256;
    const int E = in_sizes[1] / 2;
    const int* src = ei;
    const int* dst = ei + E;

    char* ws = (char*)d_ws;
    size_t off = 0;
    auto alloc = [&](size_t bytes) -> void* {
        off = (off + 255) & ~(size_t)255;
        void* p = (void*)(ws + off);
        off += bytes;
        return p;
    };
    size_t bufBytes = (size_t)n * 128 * sizeof(float);            // 8 chunks x n x 16
    size_t mirBytes = (size_t)(n + 1) * 128 * sizeof(__half);     // 8 chunks x (n+1) x 16
    float* bufA   = (float*)alloc(bufBytes);
    float* bufB   = (float*)alloc(bufBytes);
    float* bufC   = (float*)alloc(bufBytes);
    float* mirA   = (float*)alloc(mirBytes);
    float* mirB   = (float*)alloc(mirBytes);
    int*   col    = (int*)alloc((size_t)E * sizeof(int));
    int*   degs   = (int*)alloc((size_t)n * sizeof(int));
    int*   cntd   = (int*)alloc((size_t)n * sizeof(int));
    int*   rowptr = (int*)alloc((size_t)(n + 1) * sizeof(int));
    int*   cursor = (int*)alloc((size_t)n * sizeof(int));
    int*   bsum   = (int*)alloc(1024 * sizeof(int));
    float* dinv   = (float*)alloc((size_t)n * sizeof(float));

    (void)hipMemsetAsync(degs, 0, (size_t)n * sizeof(int), stream);
    (void)hipMemsetAsync(cntd, 0, (size_t)n * sizeof(int), stream);

    // ---- CSR build (by dst), col-only records ----
    hist_kernel<<<2048, 256, 0, stream>>>(src, dst, degs, cntd, E);
    dinv_kernel<<<(n + 255) / 256, 256, 0, stream>>>(degs, dinv, n);
    int nchunk = (n + SCAN_CHUNK - 1) / SCAN_CHUNK;
    scan_chunk_sum<<<nchunk, SCAN_BLOCK, 0, stream>>>(cntd, bsum, n);
    scan_bsum<<<1, 64, 0, stream>>>(bsum, nchunk);
    scan_write<<<nchunk, SCAN_BLOCK, 0, stream>>>(cntd, bsum, rowptr, cursor, n, E);
    scatter_kernel<<<4096, 256, 0, stream>>>(src, dst, cursor, col, E);

    // ---- h = relu(x @ W1 + b1) (chunk-major) + pre-scaled fp16 mirror ----
    gemm1_kernel<<<(n + G1_ROWS - 1) / G1_ROWS, 128, 0, stream>>>(x, W1, b1, bufA, n);
    dim3 mgrid(1024, 8);
    mirror_kernel<<<mgrid, 256, 0, stream>>>((const float4*)bufA, (fx2*)mirA, dinv, n);
    pad_kernel<<<1, 128, 0, stream>>>(mirA, mirB, n);

    // ---- 2 BernConv layers ----
    int pgrid = ((n + 3) / 4) * 8;  // (nodes/4 per block) x 8 feature chunks
    float* A  = bufA;
    float* B  = bufB;
    float* C  = bufC;
    float* mA = mirA;
    float* mB = mirB;
    for (int l = 0; l < 2; ++l) {
        // k=0,1 fused: tx1 = 0.5x - agg(x) -> B (+mirror mB); OUT = c0*x + c1*tx1
        prop_kernel<<<pgrid, 256, 0, stream>>>(A, mA, A, C, B, mB, rowptr, col, dinv,
                                               coeffs, l * 11 + 0, 0, n);
        float* t0 = A;  float* m0 = mA;
        float* t1 = B;  float* m1 = mB;
        for (int k = 2; k <= 9; ++k) {
            // gather from t1's mirror m1; tx2 overwrites t0 (+mirror m0)
            prop_kernel<<<pgrid, 256, 0, stream>>>(t1, m1, t0, C, nullptr, m0, rowptr,
                                                   col, dinv, coeffs, l * 11 + k, 1, n);
            float* tf = t0; t0 = t1; t1 = tf;
            float* tm = m0; m0 = m1; m1 = tm;
        }
        // k=10: fold last term + ReLU -> t0 (+mirror m0 if another layer follows)
        prop_kernel<<<pgrid, 256, 0, stream>>>(t1, m1, t0, C, nullptr,
                                               (l == 0) ? m0 : nullptr, rowptr, col,
                                               dinv, coeffs, l * 11 + 10, 2, n);
        A = t0; mA = m0;   // next layer input
        B = t1; mB = m1;
    }

    // ---- out = h @ W2 + b2 ----
    gemm2_kernel<<<(n + G2_ROWS - 1) / G2_ROWS, 64, 0, stream>>>(A, W2, b2, out, n);
}

// Round 8
// 8655.403 us; speedup vs baseline: 1.0569x; 1.0569x over previous
//
#include <hip/hip_runtime.h>
#include <hip/hip_fp16.h>

// ---------------------------------------------------------------------------
// BernNet forward: x@W1+b1 -> relu -> 2x BernConv(K=10) -> h@W2+b2
// 128 features split into 8 chunks of 16, chunk c pinned to XCD c via
// blockIdx%8; per-chunk fp16 gather mirror (3.2MB) is L2-resident per XCD
// (R7 counters: FETCH 143MB/pass vs 830MB un-chunked). Mirrors store
// u = dinv[v]*T[v] so CSR is a bare 4B col array; epilogue scales by
// -0.5*dinv[v]. Gather loop is a branch-free 4-deep unroll (4 independent
// loads in flight; R7's rolled loop at VGPR=12 serialized on L2 latency).
// Trip counts wave-uniform; padding slots read dummy zero row n (L1-hot).
// ---------------------------------------------------------------------------

#define SCAN_BLOCK 256
#define SCAN_ITEMS 4
#define SCAN_CHUNK 1024

typedef float fx2 __attribute__((ext_vector_type(2)));

union fh2 { float f; __half2 h; };
union f2h4 { fx2 f2; __half2 h2[2]; };

__global__ __launch_bounds__(256) void hist_kernel(const int* __restrict__ src,
                                                   const int* __restrict__ dst,
                                                   int* __restrict__ deg_src,
                                                   int* __restrict__ cnt_dst, int E) {
    int stride = gridDim.x * blockDim.x;
    for (int e = blockIdx.x * blockDim.x + threadIdx.x; e < E; e += stride) {
        atomicAdd(&deg_src[src[e]], 1);
        atomicAdd(&cnt_dst[dst[e]], 1);
    }
}

__global__ __launch_bounds__(256) void dinv_kernel(const int* __restrict__ deg,
                                                   float* __restrict__ dinv, int n) {
    int i = blockIdx.x * blockDim.x + threadIdx.x;
    if (i < n) {
        int d = deg[i];
        dinv[i] = d > 0 ? rsqrtf((float)d) : 0.f;
    }
}

__global__ __launch_bounds__(SCAN_BLOCK) void scan_chunk_sum(const int* __restrict__ cnt,
                                                             int* __restrict__ bsum, int n) {
    __shared__ int sdata[SCAN_BLOCK];
    int tid = threadIdx.x;
    int base = blockIdx.x * SCAN_CHUNK + tid * SCAN_ITEMS;
    int s = 0;
    for (int i = 0; i < SCAN_ITEMS; ++i) {
        int idx = base + i;
        if (idx < n) s += cnt[idx];
    }
    sdata[tid] = s;
    __syncthreads();
    for (int off = SCAN_BLOCK / 2; off > 0; off >>= 1) {
        if (tid < off) sdata[tid] += sdata[tid + off];
        __syncthreads();
    }
    if (tid == 0) bsum[blockIdx.x] = sdata[0];
}

__global__ void scan_bsum(int* __restrict__ bsum, int nb) {
    if (threadIdx.x == 0 && blockIdx.x == 0) {
        int run = 0;
        for (int i = 0; i < nb; ++i) {
            int v = bsum[i];
            bsum[i] = run;
            run += v;
        }
    }
}

__global__ __launch_bounds__(SCAN_BLOCK) void scan_write(const int* __restrict__ cnt,
                                                         const int* __restrict__ bsum,
                                                         int* __restrict__ rowptr,
                                                         int* __restrict__ cursor,
                                                         int n, int total) {
    __shared__ int sdata[SCAN_BLOCK];
    int tid = threadIdx.x;
    int base = blockIdx.x * SCAN_CHUNK + tid * SCAN_ITEMS;
    int vals[SCAN_ITEMS];
    int s = 0;
    for (int i = 0; i < SCAN_ITEMS; ++i) {
        int idx = base + i;
        vals[i] = (idx < n) ? cnt[idx] : 0;
        s += vals[i];
    }
    sdata[tid] = s;
    __syncthreads();
    for (int off = 1; off < SCAN_BLOCK; off <<= 1) {
        int add = (tid >= off) ? sdata[tid - off] : 0;
        __syncthreads();
        sdata[tid] += add;
        __syncthreads();
    }
    int run = bsum[blockIdx.x] + sdata[tid] - s;
    for (int i = 0; i < SCAN_ITEMS; ++i) {
        int idx = base + i;
        if (idx < n) {
            rowptr[idx] = run;
            cursor[idx] = run;
        }
        run += vals[i];
    }
    if (blockIdx.x == 0 && tid == 0) rowptr[n] = total;
}

// bare 4B record per edge: source index only (weights folded into mirror)
__global__ __launch_bounds__(256) void scatter_kernel(const int* __restrict__ src,
                                                      const int* __restrict__ dst,
                                                      int* __restrict__ cursor,
                                                      int* __restrict__ col, int E) {
    int stride = gridDim.x * blockDim.x;
    for (int e = blockIdx.x * blockDim.x + threadIdx.x; e < E; e += stride) {
        int d = dst[e];
        int p = atomicAdd(&cursor[d], 1);
        col[p] = src[e];
    }
}

// f32 chunk-major -> pre-scaled fp16 mirror (u = dinv[v] * h[v])
__global__ __launch_bounds__(256) void mirror_kernel(const float4* __restrict__ src,
                                                     fx2* __restrict__ dst,
                                                     const float* __restrict__ dinv,
                                                     int n) {
    int c = blockIdx.y;
    size_t cs4 = (size_t)n * 4;         // float4 per f32 chunk
    size_t csm = (size_t)(n + 1) * 4;   // fx2 per mirror chunk
    int stride = gridDim.x * blockDim.x;
    for (int i = blockIdx.x * blockDim.x + threadIdx.x; i < n * 4; i += stride) {
        int v = i >> 2;
        float dv = dinv[v];
        float4 x = src[cs4 * c + i];
        f2h4 u;
        u.h2[0] = __floats2half2_rn(x.x * dv, x.y * dv);
        u.h2[1] = __floats2half2_rn(x.z * dv, x.w * dv);
        dst[csm * c + i] = u.f2;
    }
}

// zero the dummy gather row (index n) of both mirrors
__global__ void pad_kernel(float* __restrict__ mA, float* __restrict__ mB, int n) {
    int t = threadIdx.x;  // 128 threads
    size_t csh = (size_t)(n + 1) * 8;   // dwords per mirror chunk
    int c = (t >> 3) & 7;
    int fl = t & 7;
    if (t < 64) mA[csh * c + (size_t)n * 8 + fl] = 0.f;
    else if (t < 128) mB[csh * c + (size_t)n * 8 + fl] = 0.f;
}

// -------------------- GEMM1: h = relu(x @ W1 + b1) -> chunk-major ----------
#define G1_ROWS 16
__global__ __launch_bounds__(128) void gemm1_kernel(const float* __restrict__ X,
                                                    const float* __restrict__ W,
                                                    const float* __restrict__ b,
                                                    float* __restrict__ H, int n) {
    __shared__ float xt[G1_ROWS][256];
    int j = threadIdx.x;  // output column 0..127
    int r0 = blockIdx.x * G1_ROWS;
    for (int i = threadIdx.x; i < G1_ROWS * 256; i += 128) {
        int r = i >> 8, k = i & 255;
        int row = r0 + r;
        xt[r][k] = (row < n) ? X[(size_t)row * 256 + k] : 0.f;
    }
    __syncthreads();
    float acc[G1_ROWS];
#pragma unroll
    for (int r = 0; r < G1_ROWS; ++r) acc[r] = 0.f;
    for (int k = 0; k < 256; ++k) {
        float wk = W[k * 128 + j];
#pragma unroll
        for (int r = 0; r < G1_ROWS; ++r) acc[r] += xt[r][k] * wk;
    }
    float bj = b[j];
    size_t cs32 = (size_t)n * 16;
    size_t cbase = (size_t)(j >> 4) * cs32 + (j & 15);
    for (int r = 0; r < G1_ROWS; ++r) {
        int row = r0 + r;
        if (row < n) H[cbase + (size_t)row * 16] = fmaxf(acc[r] + bj, 0.f);
    }
}

// -------------------- GEMM2: out = h(chunk-major) @ W2 + b2 ----------------
#define G2_ROWS 32
__global__ __launch_bounds__(64) void gemm2_kernel(const float* __restrict__ H,
                                                   const float* __restrict__ W,
                                                   const float* __restrict__ b,
                                                   float* __restrict__ O, int n) {
    __shared__ float xt[G2_ROWS][128];
    int j = threadIdx.x;  // output column 0..63
    int r0 = blockIdx.x * G2_ROWS;
    size_t cs32 = (size_t)n * 16;
    for (int i = threadIdx.x; i < G2_ROWS * 128; i += 64) {
        int r = i >> 7, k = i & 127;
        int row = r0 + r;
        xt[r][k] = (row < n)
            ? H[(size_t)(k >> 4) * cs32 + (size_t)row * 16 + (k & 15)] : 0.f;
    }
    __syncthreads();
    float acc[G2_ROWS];
#pragma unroll
    for (int r = 0; r < G2_ROWS; ++r) acc[r] = 0.f;
    for (int k = 0; k < 128; ++k) {
        float wk = W[k * 64 + j];
#pragma unroll
        for (int r = 0; r < G2_ROWS; ++r) acc[r] += xt[r][k] * wk;
    }
    float bj = b[j];
    for (int r = 0; r < G2_ROWS; ++r) {
        int row = r0 + r;
        if (row < n) O[(size_t)row * 64 + j] = acc[r] + bj;
    }
}

// -------------------- Fused Chebyshev propagation step (chunked) -----------
// blockIdx.x & 7 = feature chunk (-> XCD); one node per wave (4 waves/block).
// Lanes: es = lane>>3 (edge slot), fl = lane&7 (feature dword: 2 fp16).
// Gather: branch-free 4-deep unroll -- 4 hoisted shfls + 4 independent 4B
// loads per group (32 edges). Slots past m (and past iters within a group)
// read dummy zero row n, which stays L1-hot. Butterfly-reduce over es.
// agg = -0.5*dinv[v]*sum. Mirror rows store u = dinv[v]*value.
// mode 0: tx1 = 0.5x - agg -> TX1 (+MH); OUT = c0*x + c1*tx1
// mode 1: tx2 = x - 2*agg - t0; OUT += ck*tx2; T0 <- tx2 (+MH)
// mode 2: T0 <- relu(OUT + ck*tx2) (+MH)   (layer end)
__global__ __launch_bounds__(256) void prop_kernel(const float* __restrict__ XF,
                                                   const float* __restrict__ XH,
                                                   float* __restrict__ T0,
                                                   float* __restrict__ OUT,
                                                   float* __restrict__ TX1,
                                                   float* __restrict__ MH,
                                                   const int* __restrict__ rowptr,
                                                   const int* __restrict__ col,
                                                   const float* __restrict__ dinv,
                                                   const float* __restrict__ coeffs,
                                                   int cidx, int mode, int n) {
    int c = blockIdx.x & 7;
    int nb = blockIdx.x >> 3;
    int wid = threadIdx.x >> 6;
    int v = nb * 4 + wid;
    if (v >= n) return;
    int lane = threadIdx.x & 63;
    int es = lane >> 3;
    int fl = lane & 7;

    size_t csh = (size_t)(n + 1) * 8;  // dwords per mirror chunk
    const float* __restrict__ M = XH + csh * c;

    int start = rowptr[v];
    int end = rowptr[v + 1];
    fx2 a0 = {0.f, 0.f}, a1 = {0.f, 0.f}, a2 = {0.f, 0.f}, a3 = {0.f, 0.f};

    for (int e0 = start; e0 < end; e0 += 64) {
        int m = end - e0;
        if (m > 64) m = 64;
        int colv = n;  // dummy zero row for padding slots
        if (lane < m) colv = __builtin_nontemporal_load(col + e0 + lane);
        int iters = (m + 7) >> 3;  // wave-uniform
        for (int t = 0; t < iters; t += 4) {
            // 4 hoisted shuffles + 4 independent loads (slot index <= 63;
            // groups past iters read the dummy row -> contribute 0)
            int s0 = __shfl(colv, (t + 0) * 8 + es);
            int s1 = __shfl(colv, (t + 1) * 8 + es);
            int s2 = __shfl(colv, (t + 2) * 8 + es);
            int s3 = __shfl(colv, (t + 3) * 8 + es);
            fh2 u0, u1, u2, u3;
            u0.f = M[s0 * 8 + fl];
            u1.f = M[s1 * 8 + fl];
            u2.f = M[s2 * 8 + fl];
            u3.f = M[s3 * 8 + fl];
            float2 x0 = __half22float2(u0.h);
            float2 x1 = __half22float2(u1.h);
            float2 x2 = __half22float2(u2.h);
            float2 x3 = __half22float2(u3.h);
            a0.x += x0.x; a0.y += x0.y;
            a1.x += x1.x; a1.y += x1.y;
            a2.x += x2.x; a2.y += x2.y;
            a3.x += x3.x; a3.y += x3.y;
        }
    }
    fx2 acc;
    acc.x = (a0.x + a1.x) + (a2.x + a3.x);
    acc.y = (a0.y + a1.y) + (a2.y + a3.y);
    acc.x += __shfl_xor(acc.x, 8);
    acc.y += __shfl_xor(acc.y, 8);
    acc.x += __shfl_xor(acc.x, 16);
    acc.y += __shfl_xor(acc.y, 16);
    acc.x += __shfl_xor(acc.x, 32);
    acc.y += __shfl_xor(acc.y, 32);

    if (lane >= 8) return;  // lanes 0..7 hold agg for features (2*fl, 2*fl+1)

    float dv = dinv[v];
    float sw = -0.5f * dv;
    float gx = sw * acc.x;
    float gy = sw * acc.y;

    size_t i2 = (size_t)c * n * 8 + (size_t)v * 8 + fl;  // fx2 index
    const fx2* X2 = reinterpret_cast<const fx2*>(XF);
    fx2 self = __builtin_nontemporal_load(X2 + i2);
    fx2 wr;

    if (mode == 0) {
        float c0 = coeffs[cidx];
        float c1 = coeffs[cidx + 1];
        wr.x = 0.5f * self.x - gx;
        wr.y = 0.5f * self.y - gy;
        __builtin_nontemporal_store(wr, reinterpret_cast<fx2*>(TX1) + i2);
        fx2 o;
        o.x = c0 * self.x + c1 * wr.x;
        o.y = c0 * self.y + c1 * wr.y;
        __builtin_nontemporal_store(o, reinterpret_cast<fx2*>(OUT) + i2);
    } else {
        float ck = coeffs[cidx];
        fx2 t0v = __builtin_nontemporal_load(reinterpret_cast<const fx2*>(T0) + i2);
        fx2 t2;
        t2.x = self.x - 2.f * gx - t0v.x;
        t2.y = self.y - 2.f * gy - t0v.y;
        fx2 o = __builtin_nontemporal_load(reinterpret_cast<const fx2*>(OUT) + i2);
        o.x += ck * t2.x;
        o.y += ck * t2.y;
        if (mode == 1) {
            wr = t2;
            __builtin_nontemporal_store(wr, reinterpret_cast<fx2*>(T0) + i2);
            __builtin_nontemporal_store(o, reinterpret_cast<fx2*>(OUT) + i2);
        } else {
            wr.x = fmaxf(o.x, 0.f);
            wr.y = fmaxf(o.y, 0.f);
            __builtin_nontemporal_store(wr, reinterpret_cast<fx2*>(T0) + i2);
        }
    }
    if (MH) {
        fh2 u;
        u.h = __floats2half2_rn(wr.x * dv, wr.y * dv);
        MH[csh * c + (size_t)v * 8 + fl] = u.f;
    }
}

// ---------------------------------------------------------------------------

extern "C" void kernel_launch(void* const* d_in, const int* in_sizes, int n_in,
                              void* d_out, int out_size, void* d_ws, size_t ws_size,
                              hipStream_t stream) {
    const float* x      = (const float*)d_in[0];
    const int*   ei     = (const int*)d_in[1];
    const float* W1     = (const float*)d_in[2];
    const float* b1     = (const float*)d_in[3];
    const float* coeffs = (const float*)d_in[4];
    const float* W2     = (const float*)d_in[5];
    const float* b2     = (const float*)d_in[6];
    float* out = (float*)d_out;

    const int n = in_sizes[0] / 256;
    const int E = in_sizes[1] / 2;
    const int* src = ei;
    const int* dst = ei + E;

    char* ws = (char*)d_ws;
    size_t off = 0;
    auto alloc = [&](size_t bytes) -> void* {
        off = (off + 255) & ~(size_t)255;
        void* p = (void*)(ws + off);
        off += bytes;
        return p;
    };
    size_t bufBytes = (size_t)n * 128 * sizeof(float);            // 8 chunks x n x 16
    size_t mirBytes = (size_t)(n + 1) * 128 * sizeof(__half);     // 8 chunks x (n+1) x 16
    float* bufA   = (float*)alloc(bufBytes);
    float* bufB   = (float*)alloc(bufBytes);
    float* bufC   = (float*)alloc(bufBytes);
    float* mirA   = (float*)alloc(mirBytes);
    float* mirB   = (float*)alloc(mirBytes);
    int*   col    = (int*)alloc((size_t)E * sizeof(int));
    int*   degs   = (int*)alloc((size_t)n * sizeof(int));
    int*   cntd   = (int*)alloc((size_t)n * sizeof(int));
    int*   rowptr = (int*)alloc((size_t)(n + 1) * sizeof(int));
    int*   cursor = (int*)alloc((size_t)n * sizeof(int));
    int*   bsum   = (int*)alloc(1024 * sizeof(int));
    float* dinv   = (float*)alloc((size_t)n * sizeof(float));

    (void)hipMemsetAsync(degs, 0, (size_t)n * sizeof(int), stream);
    (void)hipMemsetAsync(cntd, 0, (size_t)n * sizeof(int), stream);

    // ---- CSR build (by dst), col-only records ----
    hist_kernel<<<2048, 256, 0, stream>>>(src, dst, degs, cntd, E);
    dinv_kernel<<<(n + 255) / 256, 256, 0, stream>>>(degs, dinv, n);
    int nchunk = (n + SCAN_CHUNK - 1) / SCAN_CHUNK;
    scan_chunk_sum<<<nchunk, SCAN_BLOCK, 0, stream>>>(cntd, bsum, n);
    scan_bsum<<<1, 64, 0, stream>>>(bsum, nchunk);
    scan_write<<<nchunk, SCAN_BLOCK, 0, stream>>>(cntd, bsum, rowptr, cursor, n, E);
    scatter_kernel<<<4096, 256, 0, stream>>>(src, dst, cursor, col, E);

    // ---- h = relu(x @ W1 + b1) (chunk-major) + pre-scaled fp16 mirror ----
    gemm1_kernel<<<(n + G1_ROWS - 1) / G1_ROWS, 128, 0, stream>>>(x, W1, b1, bufA, n);
    dim3 mgrid(1024, 8);
    mirror_kernel<<<mgrid, 256, 0, stream>>>((const float4*)bufA, (fx2*)mirA, dinv, n);
    pad_kernel<<<1, 128, 0, stream>>>(mirA, mirB, n);

    // ---- 2 BernConv layers ----
    int pgrid = ((n + 3) / 4) * 8;  // (nodes/4 per block) x 8 feature chunks
    float* A  = bufA;
    float* B  = bufB;
    float* C  = bufC;
    float* mA = mirA;
    float* mB = mirB;
    for (int l = 0; l < 2; ++l) {
        // k=0,1 fused: tx1 = 0.5x - agg(x) -> B (+mirror mB); OUT = c0*x + c1*tx1
        prop_kernel<<<pgrid, 256, 0, stream>>>(A, mA, A, C, B, mB, rowptr, col, dinv,
                                               coeffs, l * 11 + 0, 0, n);
        float* t0 = A;  float* m0 = mA;
        float* t1 = B;  float* m1 = mB;
        for (int k = 2; k <= 9; ++k) {
            // gather from t1's mirror m1; tx2 overwrites t0 (+mirror m0)
            prop_kernel<<<pgrid, 256, 0, stream>>>(t1, m1, t0, C, nullptr, m0, rowptr,
                                                   col, dinv, coeffs, l * 11 + k, 1, n);
            float* tf = t0; t0 = t1; t1 = tf;
            float* tm = m0; m0 = m1; m1 = tm;
        }
        // k=10: fold last term + ReLU -> t0 (+mirror m0 if another layer follows)
        prop_kernel<<<pgrid, 256, 0, stream>>>(t1, m1, t0, C, nullptr,
                                               (l == 0) ? m0 : nullptr, rowptr, col,
                                               dinv, coeffs, l * 11 + 10, 2, n);
        A = t0; mA = m0;   // next layer input
        B = t1; mB = m1;
    }

    // ---- out = h @ W2 + b2 ----
    gemm2_kernel<<<(n + G2_ROWS - 1) / G2_ROWS, 64, 0, stream>>>(A, W2, b2, out, n);
}

// Round 9
// 7251.816 us; speedup vs baseline: 1.2614x; 1.1935x over previous
//
#include <hip/hip_runtime.h>
#include <hip/hip_fp16.h>

// ---------------------------------------------------------------------------
// BernNet forward: x@W1+b1 -> relu -> 2x BernConv(K=10) -> h@W2+b2
// Feature-chunked propagation (8 chunks of 16, chunk = blockIdx%8 -> XCD;
// 3.2MB fp16 mirror per chunk is L2-resident -- R7/R8 FETCH 143MB confirms).
// R9: wave = 8 nodes x 8 feature-dwords. Each 8-lane group walks its node's
// edge list; each lane owns 2 features -> NO cross-lane ops at all (shfl-free,
// divergence-safe). CSR rows padded to x4 with dummy-row-n entries so cols
// load as one aligned int4 per 4 edges. Mirrors store u = dinv[v]*T[v];
// epilogue scales by -0.5*dinv[v]. Streaming traffic (col, f32 state) is
// nontemporal to protect mirror L2 residency; mirror writes stay temporal.
// ---------------------------------------------------------------------------

#define SCAN_BLOCK 256
#define SCAN_ITEMS 4
#define SCAN_CHUNK 1024

typedef float fx2 __attribute__((ext_vector_type(2)));
typedef int ix4 __attribute__((ext_vector_type(4)));

union fh2 { float f; __half2 h; };
union f2h4 { fx2 f2; __half2 h2[2]; };

__global__ __launch_bounds__(256) void hist_kernel(const int* __restrict__ src,
                                                   const int* __restrict__ dst,
                                                   int* __restrict__ deg_src,
                                                   int* __restrict__ cnt_dst, int E) {
    int stride = gridDim.x * blockDim.x;
    for (int e = blockIdx.x * blockDim.x + threadIdx.x; e < E; e += stride) {
        atomicAdd(&deg_src[src[e]], 1);
        atomicAdd(&cnt_dst[dst[e]], 1);
    }
}

__global__ __launch_bounds__(256) void dinv_kernel(const int* __restrict__ deg,
                                                   float* __restrict__ dinv, int n) {
    int i = blockIdx.x * blockDim.x + threadIdx.x;
    if (i < n) {
        int d = deg[i];
        dinv[i] = d > 0 ? rsqrtf((float)d) : 0.f;
    }
}

// scans use PADDED counts: each CSR row rounded up to a multiple of 4
__global__ __launch_bounds__(SCAN_BLOCK) void scan_chunk_sum(const int* __restrict__ cnt,
                                                             int* __restrict__ bsum, int n) {
    __shared__ int sdata[SCAN_BLOCK];
    int tid = threadIdx.x;
    int base = blockIdx.x * SCAN_CHUNK + tid * SCAN_ITEMS;
    int s = 0;
    for (int i = 0; i < SCAN_ITEMS; ++i) {
        int idx = base + i;
        if (idx < n) s += (cnt[idx] + 3) & ~3;
    }
    sdata[tid] = s;
    __syncthreads();
    for (int off = SCAN_BLOCK / 2; off > 0; off >>= 1) {
        if (tid < off) sdata[tid] += sdata[tid + off];
        __syncthreads();
    }
    if (tid == 0) bsum[blockIdx.x] = sdata[0];
}

__global__ void scan_bsum(int* __restrict__ bsum, int nb) {
    if (threadIdx.x == 0 && blockIdx.x == 0) {
        int run = 0;
        for (int i = 0; i < nb; ++i) {
            int v = bsum[i];
            bsum[i] = run;
            run += v;
        }
    }
}

__global__ __launch_bounds__(SCAN_BLOCK) void scan_write(const int* __restrict__ cnt,
                                                         const int* __restrict__ bsum,
                                                         int* __restrict__ rowptr,
                                                         int* __restrict__ cursor,
                                                         int n) {
    __shared__ int sdata[SCAN_BLOCK];
    int tid = threadIdx.x;
    int base = blockIdx.x * SCAN_CHUNK + tid * SCAN_ITEMS;
    int vals[SCAN_ITEMS];
    int s = 0;
    for (int i = 0; i < SCAN_ITEMS; ++i) {
        int idx = base + i;
        vals[i] = (idx < n) ? ((cnt[idx] + 3) & ~3) : 0;
        s += vals[i];
    }
    sdata[tid] = s;
    __syncthreads();
    for (int off = 1; off < SCAN_BLOCK; off <<= 1) {
        int add = (tid >= off) ? sdata[tid - off] : 0;
        __syncthreads();
        sdata[tid] += add;
        __syncthreads();
    }
    int run = bsum[blockIdx.x] + sdata[tid] - s;
    for (int i = 0; i < SCAN_ITEMS; ++i) {
        int idx = base + i;
        if (idx < n) {
            rowptr[idx] = run;
            cursor[idx] = run;
        }
        run += vals[i];
    }
    // rowptr[n] set by last chunk's last thread with items
    if (base + SCAN_ITEMS >= n && base < n) {
        rowptr[n] = run;
    }
}

// pre-fill padded col array with dummy row index n
__global__ __launch_bounds__(256) void fillcol_kernel(int* __restrict__ col, int total, int n) {
    int stride = gridDim.x * blockDim.x;
    for (int i = blockIdx.x * blockDim.x + threadIdx.x; i < total; i += stride)
        col[i] = n;
}

// bare 4B record per edge: source index only (weights folded into mirror)
__global__ __launch_bounds__(256) void scatter_kernel(const int* __restrict__ src,
                                                      const int* __restrict__ dst,
                                                      int* __restrict__ cursor,
                                                      int* __restrict__ col, int E) {
    int stride = gridDim.x * blockDim.x;
    for (int e = blockIdx.x * blockDim.x + threadIdx.x; e < E; e += stride) {
        int d = dst[e];
        int p = atomicAdd(&cursor[d], 1);
        col[p] = src[e];
    }
}

// f32 chunk-major -> pre-scaled fp16 mirror (u = dinv[v] * h[v])
__global__ __launch_bounds__(256) void mirror_kernel(const float4* __restrict__ src,
                                                     fx2* __restrict__ dst,
                                                     const float* __restrict__ dinv,
                                                     int n) {
    int c = blockIdx.y;
    size_t cs4 = (size_t)n * 4;         // float4 per f32 chunk
    size_t csm = (size_t)(n + 1) * 4;   // fx2 per mirror chunk
    int stride = gridDim.x * blockDim.x;
    for (int i = blockIdx.x * blockDim.x + threadIdx.x; i < n * 4; i += stride) {
        int v = i >> 2;
        float dv = dinv[v];
        float4 x = src[cs4 * c + i];
        f2h4 u;
        u.h2[0] = __floats2half2_rn(x.x * dv, x.y * dv);
        u.h2[1] = __floats2half2_rn(x.z * dv, x.w * dv);
        dst[csm * c + i] = u.f2;
    }
}

// zero the dummy gather row (index n) of both mirrors
__global__ void pad_kernel(float* __restrict__ mA, float* __restrict__ mB, int n) {
    int t = threadIdx.x;  // 128 threads
    size_t csh = (size_t)(n + 1) * 8;   // dwords per mirror chunk
    int c = (t >> 3) & 7;
    int fl = t & 7;
    if (t < 64) mA[csh * c + (size_t)n * 8 + fl] = 0.f;
    else if (t < 128) mB[csh * c + (size_t)n * 8 + fl] = 0.f;
}

// -------------------- GEMM1: h = relu(x @ W1 + b1) -> chunk-major ----------
#define G1_ROWS 16
__global__ __launch_bounds__(128) void gemm1_kernel(const float* __restrict__ X,
                                                    const float* __restrict__ W,
                                                    const float* __restrict__ b,
                                                    float* __restrict__ H, int n) {
    __shared__ float xt[G1_ROWS][256];
    int j = threadIdx.x;  // output column 0..127
    int r0 = blockIdx.x * G1_ROWS;
    for (int i = threadIdx.x; i < G1_ROWS * 256; i += 128) {
        int r = i >> 8, k = i & 255;
        int row = r0 + r;
        xt[r][k] = (row < n) ? X[(size_t)row * 256 + k] : 0.f;
    }
    __syncthreads();
    float acc[G1_ROWS];
#pragma unroll
    for (int r = 0; r < G1_ROWS; ++r) acc[r] = 0.f;
    for (int k = 0; k < 256; ++k) {
        float wk = W[k * 128 + j];
#pragma unroll
        for (int r = 0; r < G1_ROWS; ++r) acc[r] += xt[r][k] * wk;
    }
    float bj = b[j];
    size_t cs32 = (size_t)n * 16;
    size_t cbase = (size_t)(j >> 4) * cs32 + (j & 15);
    for (int r = 0; r < G1_ROWS; ++r) {
        int row = r0 + r;
        if (row < n) H[cbase + (size_t)row * 16] = fmaxf(acc[r] + bj, 0.f);
    }
}

// -------------------- GEMM2: out = h(chunk-major) @ W2 + b2 ----------------
#define G2_ROWS 32
__global__ __launch_bounds__(64) void gemm2_kernel(const float* __restrict__ H,
                                                   const float* __restrict__ W,
                                                   const float* __restrict__ b,
                                                   float* __restrict__ O, int n) {
    __shared__ float xt[G2_ROWS][128];
    int j = threadIdx.x;  // output column 0..63
    int r0 = blockIdx.x * G2_ROWS;
    size_t cs32 = (size_t)n * 16;
    for (int i = threadIdx.x; i < G2_ROWS * 128; i += 64) {
        int r = i >> 7, k = i & 127;
        int row = r0 + r;
        xt[r][k] = (row < n)
            ? H[(size_t)(k >> 4) * cs32 + (size_t)row * 16 + (k & 15)] : 0.f;
    }
    __syncthreads();
    float acc[G2_ROWS];
#pragma unroll
    for (int r = 0; r < G2_ROWS; ++r) acc[r] = 0.f;
    for (int k = 0; k < 128; ++k) {
        float wk = W[k * 64 + j];
#pragma unroll
        for (int r = 0; r < G2_ROWS; ++r) acc[r] += xt[r][k] * wk;
    }
    float bj = b[j];
    for (int r = 0; r < G2_ROWS; ++r) {
        int row = r0 + r;
        if (row < n) O[(size_t)row * 64 + j] = acc[r] + bj;
    }
}

// -------------------- Fused Chebyshev propagation step (chunked) -----------
// blockIdx.x & 7 = feature chunk (-> XCD). Wave = 8 nodes x 8 feature-dwords:
// g = lane>>3 (node slot), fl = lane&7 (dword = 2 fp16 features). Each 8-lane
// group walks its node's padded edge list (one int4 col load per 4 edges);
// each lane accumulates ITS 2 features -> no cross-lane ops anywhere, so
// per-group divergent trip counts are safe. Padded col entries index dummy
// zero row n. agg = -0.5*dinv[v]*sum. Mirror rows store u = dinv[v]*value.
// mode 0: tx1 = 0.5x - agg -> TX1 (+MH); OUT = c0*x + c1*tx1
// mode 1: tx2 = x - 2*agg - t0; OUT += ck*tx2; T0 <- tx2 (+MH)
// mode 2: T0 <- relu(OUT + ck*tx2) (+MH)   (layer end)
__global__ __launch_bounds__(256) void prop_kernel(const float* __restrict__ XF,
                                                   const float* __restrict__ XH,
                                                   float* __restrict__ T0,
                                                   float* __restrict__ OUT,
                                                   float* __restrict__ TX1,
                                                   float* __restrict__ MH,
                                                   const int* __restrict__ rowptr,
                                                   const int* __restrict__ col,
                                                   const float* __restrict__ dinv,
                                                   const float* __restrict__ coeffs,
                                                   int cidx, int mode, int n) {
    int c = blockIdx.x & 7;
    int nb = blockIdx.x >> 3;
    int lane = threadIdx.x & 63;
    int wid = threadIdx.x >> 6;
    int g = lane >> 3;
    int fl = lane & 7;
    int v = nb * 32 + wid * 8 + g;
    bool valid = (v < n);

    size_t csh = (size_t)(n + 1) * 8;  // dwords per mirror chunk
    const float* __restrict__ M = XH + csh * c;

    int start = 0, end = 0;
    if (valid) {
        start = rowptr[v];
        end = rowptr[v + 1];
    }

    fx2 a0 = {0.f, 0.f}, a1 = {0.f, 0.f}, a2 = {0.f, 0.f}, a3 = {0.f, 0.f};

    // padded rows: (end-start) % 4 == 0, start 16B-aligned
    for (int e = start; e < end; e += 4) {
        ix4 cs = __builtin_nontemporal_load(reinterpret_cast<const ix4*>(col + e));
        fh2 u0, u1, u2, u3;
        u0.f = M[(size_t)cs.x * 8 + fl];
        u1.f = M[(size_t)cs.y * 8 + fl];
        u2.f = M[(size_t)cs.z * 8 + fl];
        u3.f = M[(size_t)cs.w * 8 + fl];
        float2 x0 = __half22float2(u0.h);
        float2 x1 = __half22float2(u1.h);
        float2 x2 = __half22float2(u2.h);
        float2 x3 = __half22float2(u3.h);
        a0.x += x0.x; a0.y += x0.y;
        a1.x += x1.x; a1.y += x1.y;
        a2.x += x2.x; a2.y += x2.y;
        a3.x += x3.x; a3.y += x3.y;
    }
    if (!valid) return;  // no cross-lane ops below

    float sx = (a0.x + a1.x) + (a2.x + a3.x);
    float sy = (a0.y + a1.y) + (a2.y + a3.y);

    float dv = dinv[v];
    float sw = -0.5f * dv;
    float gx = sw * sx;
    float gy = sw * sy;

    size_t i2 = (size_t)c * n * 8 + (size_t)v * 8 + fl;  // fx2 index
    const fx2* X2 = reinterpret_cast<const fx2*>(XF);
    fx2 self = __builtin_nontemporal_load(X2 + i2);
    fx2 wr;

    if (mode == 0) {
        float c0 = coeffs[cidx];
        float c1 = coeffs[cidx + 1];
        wr.x = 0.5f * self.x - gx;
        wr.y = 0.5f * self.y - gy;
        __builtin_nontemporal_store(wr, reinterpret_cast<fx2*>(TX1) + i2);
        fx2 o;
        o.x = c0 * self.x + c1 * wr.x;
        o.y = c0 * self.y + c1 * wr.y;
        __builtin_nontemporal_store(o, reinterpret_cast<fx2*>(OUT) + i2);
    } else {
        float ck = coeffs[cidx];
        fx2 t0v = __builtin_nontemporal_load(reinterpret_cast<const fx2*>(T0) + i2);
        fx2 t2;
        t2.x = self.x - 2.f * gx - t0v.x;
        t2.y = self.y - 2.f * gy - t0v.y;
        fx2 o = __builtin_nontemporal_load(reinterpret_cast<const fx2*>(OUT) + i2);
        o.x += ck * t2.x;
        o.y += ck * t2.y;
        if (mode == 1) {
            wr = t2;
            __builtin_nontemporal_store(wr, reinterpret_cast<fx2*>(T0) + i2);
            __builtin_nontemporal_store(o, reinterpret_cast<fx2*>(OUT) + i2);
        } else {
            wr.x = fmaxf(o.x, 0.f);
            wr.y = fmaxf(o.y, 0.f);
            __builtin_nontemporal_store(wr, reinterpret_cast<fx2*>(T0) + i2);
        }
    }
    if (MH) {
        fh2 u;
        u.h = __floats2half2_rn(wr.x * dv, wr.y * dv);
        MH[csh * c + (size_t)v * 8 + fl] = u.f;  // temporal: next pass reads it
    }
}

// ---------------------------------------------------------------------------

extern "C" void kernel_launch(void* const* d_in, const int* in_sizes, int n_in,
                              void* d_out, int out_size, void* d_ws, size_t ws_size,
                              hipStream_t stream) {
    const float* x      = (const float*)d_in[0];
    const int*   ei     = (const int*)d_in[1];
    const float* W1     = (const float*)d_in[2];
    const float* b1     = (const float*)d_in[3];
    const float* coeffs = (const float*)d_in[4];
    const float* W2     = (const float*)d_in[5];
    const float* b2     = (const float*)d_in[6];
    float* out = (float*)d_out;

    const int n = in_sizes[0] / 256;
    const int E = in_sizes[1] / 2;
    const int* src = ei;
    const int* dst = ei + E;
    const int Epad = E + 4 * n;  // padded col capacity

    char* ws = (char*)d_ws;
    size_t off = 0;
    auto alloc = [&](size_t bytes) -> void* {
        off = (off + 255) & ~(size_t)255;
        void* p = (void*)(ws + off);
        off += bytes;
        return p;
    };
    size_t bufBytes = (size_t)n * 128 * sizeof(float);            // 8 chunks x n x 16
    size_t mirBytes = (size_t)(n + 1) * 128 * sizeof(__half);     // 8 chunks x (n+1) x 16
    float* bufA   = (float*)alloc(bufBytes);
    float* bufB   = (float*)alloc(bufBytes);
    float* bufC   = (float*)alloc(bufBytes);
    float* mirA   = (float*)alloc(mirBytes);
    float* mirB   = (float*)alloc(mirBytes);
    int*   col    = (int*)alloc((size_t)Epad * sizeof(int));
    int*   degs   = (int*)alloc((size_t)n * sizeof(int));
    int*   cntd   = (int*)alloc((size_t)n * sizeof(int));
    int*   rowptr = (int*)alloc((size_t)(n + 1) * sizeof(int));
    int*   cursor = (int*)alloc((size_t)n * sizeof(int));
    int*   bsum   = (int*)alloc(1024 * sizeof(int));
    float* dinv   = (float*)alloc((size_t)n * sizeof(float));

    (void)hipMemsetAsync(degs, 0, (size_t)n * sizeof(int), stream);
    (void)hipMemsetAsync(cntd, 0, (size_t)n * sizeof(int), stream);

    // ---- CSR build (by dst), padded to x4 rows, col-only records ----
    hist_kernel<<<2048, 256, 0, stream>>>(src, dst, degs, cntd, E);
    dinv_kernel<<<(n + 255) / 256, 256, 0, stream>>>(degs, dinv, n);
    int nchunk = (n + SCAN_CHUNK - 1) / SCAN_CHUNK;
    scan_chunk_sum<<<nchunk, SCAN_BLOCK, 0, stream>>>(cntd, bsum, n);
    scan_bsum<<<1, 64, 0, stream>>>(bsum, nchunk);
    scan_write<<<nchunk, SCAN_BLOCK, 0, stream>>>(cntd, bsum, rowptr, cursor, n);
    fillcol_kernel<<<2048, 256, 0, stream>>>(col, Epad, n);
    scatter_kernel<<<4096, 256, 0, stream>>>(src, dst, cursor, col, E);

    // ---- h = relu(x @ W1 + b1) (chunk-major) + pre-scaled fp16 mirror ----
    gemm1_kernel<<<(n + G1_ROWS - 1) / G1_ROWS, 128, 0, stream>>>(x, W1, b1, bufA, n);
    dim3 mgrid(1024, 8);
    mirror_kernel<<<mgrid, 256, 0, stream>>>((const float4*)bufA, (fx2*)mirA, dinv, n);
    pad_kernel<<<1, 128, 0, stream>>>(mirA, mirB, n);

    // ---- 2 BernConv layers ----
    int pgrid = ((n + 31) / 32) * 8;  // 32 nodes per block x 8 feature chunks
    float* A  = bufA;
    float* B  = bufB;
    float* C  = bufC;
    float* mA = mirA;
    float* mB = mirB;
    for (int l = 0; l < 2; ++l) {
        // k=0,1 fused: tx1 = 0.5x - agg(x) -> B (+mirror mB); OUT = c0*x + c1*tx1
        prop_kernel<<<pgrid, 256, 0, stream>>>(A, mA, A, C, B, mB, rowptr, col, dinv,
                                               coeffs, l * 11 + 0, 0, n);
        float* t0 = A;  float* m0 = mA;
        float* t1 = B;  float* m1 = mB;
        for (int k = 2; k <= 9; ++k) {
            // gather from t1's mirror m1; tx2 overwrites t0 (+mirror m0)
            prop_kernel<<<pgrid, 256, 0, stream>>>(t1, m1, t0, C, nullptr, m0, rowptr,
                                                   col, dinv, coeffs, l * 11 + k, 1, n);
            float* tf = t0; t0 = t1; t1 = tf;
            float* tm = m0; m0 = m1; m1 = tm;
        }
        // k=10: fold last term + ReLU -> t0 (+mirror m0 if another layer follows)
        prop_kernel<<<pgrid, 256, 0, stream>>>(t1, m1, t0, C, nullptr,
                                               (l == 0) ? m0 : nullptr, rowptr, col,
                                               dinv, coeffs, l * 11 + 10, 2, n);
        A = t0; mA = m0;   // next layer input
        B = t1; mB = m1;
    }

    // ---- out = h @ W2 + b2 ----
    gemm2_kernel<<<(n + G2_ROWS - 1) / G2_ROWS, 64, 0, stream>>>(A, W2, b2, out, n);
}

// Round 10
// 6293.866 us; speedup vs baseline: 1.4534x; 1.1522x over previous
//
#include <hip/hip_runtime.h>
#include <hip/hip_fp16.h>

// ---------------------------------------------------------------------------
// BernNet forward: x@W1+b1 -> relu -> 2x BernConv(K=10) -> h@W2+b2
// Feature-chunked propagation (8 chunks of 16 features, chunk = blockIdx%8 ->
// XCD; 3.2MB fp16 mirror per chunk is L2-resident: R8/R9 FETCH confirms).
// Wave = 8 nodes x 8 feature-dwords, no cross-lane ops. R10: CSR rows padded
// to x16; inner loop does 4 int4 col loads + 16 independent gathers per
// iteration -> one col-wait + one gather-wait per 16 edges (R9 paid 2 waits
// per 4 edges and was round-trip-latency bound at 1.4 TB/s effective).
// Dummy col entries index zero row n (L1-hot). Mirrors store u = dinv[v]*T[v];
// epilogue scales by -0.5*dinv[v]. Streaming traffic is nontemporal.
// ---------------------------------------------------------------------------

#define SCAN_BLOCK 256
#define SCAN_ITEMS 4
#define SCAN_CHUNK 1024

typedef float fx2 __attribute__((ext_vector_type(2)));
typedef int ix4 __attribute__((ext_vector_type(4)));

union fh2 { float f; __half2 h; };
union f2h4 { fx2 f2; __half2 h2[2]; };

__global__ __launch_bounds__(256) void hist_kernel(const int* __restrict__ src,
                                                   const int* __restrict__ dst,
                                                   int* __restrict__ deg_src,
                                                   int* __restrict__ cnt_dst, int E) {
    int stride = gridDim.x * blockDim.x;
    for (int e = blockIdx.x * blockDim.x + threadIdx.x; e < E; e += stride) {
        atomicAdd(&deg_src[src[e]], 1);
        atomicAdd(&cnt_dst[dst[e]], 1);
    }
}

__global__ __launch_bounds__(256) void dinv_kernel(const int* __restrict__ deg,
                                                   float* __restrict__ dinv, int n) {
    int i = blockIdx.x * blockDim.x + threadIdx.x;
    if (i < n) {
        int d = deg[i];
        dinv[i] = d > 0 ? rsqrtf((float)d) : 0.f;
    }
}

// scans use PADDED counts: each CSR row rounded up to a multiple of 16
__global__ __launch_bounds__(SCAN_BLOCK) void scan_chunk_sum(const int* __restrict__ cnt,
                                                             int* __restrict__ bsum, int n) {
    __shared__ int sdata[SCAN_BLOCK];
    int tid = threadIdx.x;
    int base = blockIdx.x * SCAN_CHUNK + tid * SCAN_ITEMS;
    int s = 0;
    for (int i = 0; i < SCAN_ITEMS; ++i) {
        int idx = base + i;
        if (idx < n) s += (cnt[idx] + 15) & ~15;
    }
    sdata[tid] = s;
    __syncthreads();
    for (int off = SCAN_BLOCK / 2; off > 0; off >>= 1) {
        if (tid < off) sdata[tid] += sdata[tid + off];
        __syncthreads();
    }
    if (tid == 0) bsum[blockIdx.x] = sdata[0];
}

__global__ void scan_bsum(int* __restrict__ bsum, int nb) {
    if (threadIdx.x == 0 && blockIdx.x == 0) {
        int run = 0;
        for (int i = 0; i < nb; ++i) {
            int v = bsum[i];
            bsum[i] = run;
            run += v;
        }
    }
}

__global__ __launch_bounds__(SCAN_BLOCK) void scan_write(const int* __restrict__ cnt,
                                                         const int* __restrict__ bsum,
                                                         int* __restrict__ rowptr,
                                                         int* __restrict__ cursor,
                                                         int n) {
    __shared__ int sdata[SCAN_BLOCK];
    int tid = threadIdx.x;
    int base = blockIdx.x * SCAN_CHUNK + tid * SCAN_ITEMS;
    int vals[SCAN_ITEMS];
    int s = 0;
    for (int i = 0; i < SCAN_ITEMS; ++i) {
        int idx = base + i;
        vals[i] = (idx < n) ? ((cnt[idx] + 15) & ~15) : 0;
        s += vals[i];
    }
    sdata[tid] = s;
    __syncthreads();
    for (int off = 1; off < SCAN_BLOCK; off <<= 1) {
        int add = (tid >= off) ? sdata[tid - off] : 0;
        __syncthreads();
        sdata[tid] += add;
        __syncthreads();
    }
    int run = bsum[blockIdx.x] + sdata[tid] - s;
    for (int i = 0; i < SCAN_ITEMS; ++i) {
        int idx = base + i;
        if (idx < n) {
            rowptr[idx] = run;
            cursor[idx] = run;
        }
        run += vals[i];
    }
    // rowptr[n] set by the one thread whose range contains element n-1
    if (base + SCAN_ITEMS >= n && base < n) {
        rowptr[n] = run;
    }
}

// pre-fill padded col array with dummy row index n
__global__ __launch_bounds__(256) void fillcol_kernel(int* __restrict__ col, int total, int n) {
    int stride = gridDim.x * blockDim.x;
    for (int i = blockIdx.x * blockDim.x + threadIdx.x; i < total; i += stride)
        col[i] = n;
}

// bare 4B record per edge: source index only (weights folded into mirror)
__global__ __launch_bounds__(256) void scatter_kernel(const int* __restrict__ src,
                                                      const int* __restrict__ dst,
                                                      int* __restrict__ cursor,
                                                      int* __restrict__ col, int E) {
    int stride = gridDim.x * blockDim.x;
    for (int e = blockIdx.x * blockDim.x + threadIdx.x; e < E; e += stride) {
        int d = dst[e];
        int p = atomicAdd(&cursor[d], 1);
        col[p] = src[e];
    }
}

// f32 chunk-major -> pre-scaled fp16 mirror (u = dinv[v] * h[v])
__global__ __launch_bounds__(256) void mirror_kernel(const float4* __restrict__ src,
                                                     fx2* __restrict__ dst,
                                                     const float* __restrict__ dinv,
                                                     int n) {
    int c = blockIdx.y;
    size_t cs4 = (size_t)n * 4;         // float4 per f32 chunk
    size_t csm = (size_t)(n + 1) * 4;   // fx2 per mirror chunk
    int stride = gridDim.x * blockDim.x;
    for (int i = blockIdx.x * blockDim.x + threadIdx.x; i < n * 4; i += stride) {
        int v = i >> 2;
        float dv = dinv[v];
        float4 x = src[cs4 * c + i];
        f2h4 u;
        u.h2[0] = __floats2half2_rn(x.x * dv, x.y * dv);
        u.h2[1] = __floats2half2_rn(x.z * dv, x.w * dv);
        dst[csm * c + i] = u.f2;
    }
}

// zero the dummy gather row (index n) of both mirrors
__global__ void pad_kernel(float* __restrict__ mA, float* __restrict__ mB, int n) {
    int t = threadIdx.x;  // 128 threads
    size_t csh = (size_t)(n + 1) * 8;   // dwords per mirror chunk
    int c = (t >> 3) & 7;
    int fl = t & 7;
    if (t < 64) mA[csh * c + (size_t)n * 8 + fl] = 0.f;
    else if (t < 128) mB[csh * c + (size_t)n * 8 + fl] = 0.f;
}

// -------------------- GEMM1: h = relu(x @ W1 + b1) -> chunk-major ----------
#define G1_ROWS 16
__global__ __launch_bounds__(128) void gemm1_kernel(const float* __restrict__ X,
                                                    const float* __restrict__ W,
                                                    const float* __restrict__ b,
                                                    float* __restrict__ H, int n) {
    __shared__ float xt[G1_ROWS][256];
    int j = threadIdx.x;  // output column 0..127
    int r0 = blockIdx.x * G1_ROWS;
    for (int i = threadIdx.x; i < G1_ROWS * 256; i += 128) {
        int r = i >> 8, k = i & 255;
        int row = r0 + r;
        xt[r][k] = (row < n) ? X[(size_t)row * 256 + k] : 0.f;
    }
    __syncthreads();
    float acc[G1_ROWS];
#pragma unroll
    for (int r = 0; r < G1_ROWS; ++r) acc[r] = 0.f;
    for (int k = 0; k < 256; ++k) {
        float wk = W[k * 128 + j];
#pragma unroll
        for (int r = 0; r < G1_ROWS; ++r) acc[r] += xt[r][k] * wk;
    }
    float bj = b[j];
    size_t cs32 = (size_t)n * 16;
    size_t cbase = (size_t)(j >> 4) * cs32 + (j & 15);
    for (int r = 0; r < G1_ROWS; ++r) {
        int row = r0 + r;
        if (row < n) H[cbase + (size_t)row * 16] = fmaxf(acc[r] + bj, 0.f);
    }
}

// -------------------- GEMM2: out = h(chunk-major) @ W2 + b2 ----------------
#define G2_ROWS 32
__global__ __launch_bounds__(64) void gemm2_kernel(const float* __restrict__ H,
                                                   const float* __restrict__ W,
                                                   const float* __restrict__ b,
                                                   float* __restrict__ O, int n) {
    __shared__ float xt[G2_ROWS][128];
    int j = threadIdx.x;  // output column 0..63
    int r0 = blockIdx.x * G2_ROWS;
    size_t cs32 = (size_t)n * 16;
    for (int i = threadIdx.x; i < G2_ROWS * 128; i += 64) {
        int r = i >> 7, k = i & 127;
        int row = r0 + r;
        xt[r][k] = (row < n)
            ? H[(size_t)(k >> 4) * cs32 + (size_t)row * 16 + (k & 15)] : 0.f;
    }
    __syncthreads();
    float acc[G2_ROWS];
#pragma unroll
    for (int r = 0; r < G2_ROWS; ++r) acc[r] = 0.f;
    for (int k = 0; k < 128; ++k) {
        float wk = W[k * 64 + j];
#pragma unroll
        for (int r = 0; r < G2_ROWS; ++r) acc[r] += xt[r][k] * wk;
    }
    float bj = b[j];
    for (int r = 0; r < G2_ROWS; ++r) {
        int row = r0 + r;
        if (row < n) O[(size_t)row * 64 + j] = acc[r] + bj;
    }
}

// -------------------- Fused Chebyshev propagation step (chunked) -----------
// blockIdx.x & 7 = feature chunk (-> XCD). Wave = 8 nodes x 8 feature-dwords:
// g = lane>>3 (node slot), fl = lane&7 (dword = 2 fp16 features). Each 8-lane
// group walks its node's x16-padded edge list: per iteration 4 int4 col loads
// + 16 independent 4B gathers -> one col-wait + one gather-wait per 16 edges.
// Dummy entries index zero row n (L1-hot, contribute 0). No cross-lane ops.
// agg = -0.5*dinv[v]*sum. Mirror rows store u = dinv[v]*value.
// mode 0: tx1 = 0.5x - agg -> TX1 (+MH); OUT = c0*x + c1*tx1
// mode 1: tx2 = x - 2*agg - t0; OUT += ck*tx2; T0 <- tx2 (+MH)
// mode 2: T0 <- relu(OUT + ck*tx2) (+MH)   (layer end)
__global__ __launch_bounds__(256) void prop_kernel(const float* __restrict__ XF,
                                                   const float* __restrict__ XH,
                                                   float* __restrict__ T0,
                                                   float* __restrict__ OUT,
                                                   float* __restrict__ TX1,
                                                   float* __restrict__ MH,
                                                   const int* __restrict__ rowptr,
                                                   const int* __restrict__ col,
                                                   const float* __restrict__ dinv,
                                                   const float* __restrict__ coeffs,
                                                   int cidx, int mode, int n) {
    int c = blockIdx.x & 7;
    int nb = blockIdx.x >> 3;
    int lane = threadIdx.x & 63;
    int wid = threadIdx.x >> 6;
    int g = lane >> 3;
    int fl = lane & 7;
    int v = nb * 32 + wid * 8 + g;
    bool valid = (v < n);

    size_t csh = (size_t)(n + 1) * 8;  // dwords per mirror chunk
    const float* __restrict__ M = XH + csh * c;

    int start = 0, end = 0;
    if (valid) {
        start = rowptr[v];
        end = rowptr[v + 1];
    }

    fx2 a0 = {0.f, 0.f}, a1 = {0.f, 0.f}, a2 = {0.f, 0.f}, a3 = {0.f, 0.f};
    fx2 a4 = {0.f, 0.f}, a5 = {0.f, 0.f}, a6 = {0.f, 0.f}, a7 = {0.f, 0.f};

    // padded rows: (end-start) % 16 == 0, start 16B-aligned
    for (int e = start; e < end; e += 16) {
        ix4 q0 = __builtin_nontemporal_load(reinterpret_cast<const ix4*>(col + e));
        ix4 q1 = __builtin_nontemporal_load(reinterpret_cast<const ix4*>(col + e + 4));
        ix4 q2 = __builtin_nontemporal_load(reinterpret_cast<const ix4*>(col + e + 8));
        ix4 q3 = __builtin_nontemporal_load(reinterpret_cast<const ix4*>(col + e + 12));
        fh2 u0, u1, u2, u3, u4, u5, u6, u7, u8, u9, ua, ub, uc, ud, ue, uf;
        u0.f = M[(size_t)q0.x * 8 + fl];
        u1.f = M[(size_t)q0.y * 8 + fl];
        u2.f = M[(size_t)q0.z * 8 + fl];
        u3.f = M[(size_t)q0.w * 8 + fl];
        u4.f = M[(size_t)q1.x * 8 + fl];
        u5.f = M[(size_t)q1.y * 8 + fl];
        u6.f = M[(size_t)q1.z * 8 + fl];
        u7.f = M[(size_t)q1.w * 8 + fl];
        u8.f = M[(size_t)q2.x * 8 + fl];
        u9.f = M[(size_t)q2.y * 8 + fl];
        ua.f = M[(size_t)q2.z * 8 + fl];
        ub.f = M[(size_t)q2.w * 8 + fl];
        uc.f = M[(size_t)q3.x * 8 + fl];
        ud.f = M[(size_t)q3.y * 8 + fl];
        ue.f = M[(size_t)q3.z * 8 + fl];
        uf.f = M[(size_t)q3.w * 8 + fl];
        float2 x0 = __half22float2(u0.h);
        float2 x1 = __half22float2(u1.h);
        float2 x2 = __half22float2(u2.h);
        float2 x3 = __half22float2(u3.h);
        float2 x4 = __half22float2(u4.h);
        float2 x5 = __half22float2(u5.h);
        float2 x6 = __half22float2(u6.h);
        float2 x7 = __half22float2(u7.h);
        float2 x8 = __half22float2(u8.h);
        float2 x9 = __half22float2(u9.h);
        float2 xa = __half22float2(ua.h);
        float2 xb = __half22float2(ub.h);
        float2 xc = __half22float2(uc.h);
        float2 xd = __half22float2(ud.h);
        float2 xe = __half22float2(ue.h);
        float2 xf = __half22float2(uf.h);
        a0.x += x0.x; a0.y += x0.y;
        a1.x += x1.x; a1.y += x1.y;
        a2.x += x2.x; a2.y += x2.y;
        a3.x += x3.x; a3.y += x3.y;
        a4.x += x4.x; a4.y += x4.y;
        a5.x += x5.x; a5.y += x5.y;
        a6.x += x6.x; a6.y += x6.y;
        a7.x += x7.x; a7.y += x7.y;
        a0.x += x8.x; a0.y += x8.y;
        a1.x += x9.x; a1.y += x9.y;
        a2.x += xa.x; a2.y += xa.y;
        a3.x += xb.x; a3.y += xb.y;
        a4.x += xc.x; a4.y += xc.y;
        a5.x += xd.x; a5.y += xd.y;
        a6.x += xe.x; a6.y += xe.y;
        a7.x += xf.x; a7.y += xf.y;
    }
    if (!valid) return;  // no cross-lane ops below

    float sx = ((a0.x + a1.x) + (a2.x + a3.x)) + ((a4.x + a5.x) + (a6.x + a7.x));
    float sy = ((a0.y + a1.y) + (a2.y + a3.y)) + ((a4.y + a5.y) + (a6.y + a7.y));

    float dv = dinv[v];
    float sw = -0.5f * dv;
    float gx = sw * sx;
    float gy = sw * sy;

    size_t i2 = (size_t)c * n * 8 + (size_t)v * 8 + fl;  // fx2 index
    const fx2* X2 = reinterpret_cast<const fx2*>(XF);
    fx2 self = __builtin_nontemporal_load(X2 + i2);
    fx2 wr;

    if (mode == 0) {
        float c0 = coeffs[cidx];
        float c1 = coeffs[cidx + 1];
        wr.x = 0.5f * self.x - gx;
        wr.y = 0.5f * self.y - gy;
        __builtin_nontemporal_store(wr, reinterpret_cast<fx2*>(TX1) + i2);
        fx2 o;
        o.x = c0 * self.x + c1 * wr.x;
        o.y = c0 * self.y + c1 * wr.y;
        __builtin_nontemporal_store(o, reinterpret_cast<fx2*>(OUT) + i2);
    } else {
        float ck = coeffs[cidx];
        fx2 t0v = __builtin_nontemporal_load(reinterpret_cast<const fx2*>(T0) + i2);
        fx2 t2;
        t2.x = self.x - 2.f * gx - t0v.x;
        t2.y = self.y - 2.f * gy - t0v.y;
        fx2 o = __builtin_nontemporal_load(reinterpret_cast<const fx2*>(OUT) + i2);
        o.x += ck * t2.x;
        o.y += ck * t2.y;
        if (mode == 1) {
            wr = t2;
            __builtin_nontemporal_store(wr, reinterpret_cast<fx2*>(T0) + i2);
            __builtin_nontemporal_store(o, reinterpret_cast<fx2*>(OUT) + i2);
        } else {
            wr.x = fmaxf(o.x, 0.f);
            wr.y = fmaxf(o.y, 0.f);
            __builtin_nontemporal_store(wr, reinterpret_cast<fx2*>(T0) + i2);
        }
    }
    if (MH) {
        fh2 u;
        u.h = __floats2half2_rn(wr.x * dv, wr.y * dv);
        MH[csh * c + (size_t)v * 8 + fl] = u.f;  // temporal: next pass reads it
    }
}

// ---------------------------------------------------------------------------

extern "C" void kernel_launch(void* const* d_in, const int* in_sizes, int n_in,
                              void* d_out, int out_size, void* d_ws, size_t ws_size,
                              hipStream_t stream) {
    const float* x      = (const float*)d_in[0];
    const int*   ei     = (const int*)d_in[1];
    const float* W1     = (const float*)d_in[2];
    const float* b1     = (const float*)d_in[3];
    const float* coeffs = (const float*)d_in[4];
    const float* W2     = (const float*)d_in[5];
    const float* b2     = (const float*)d_in[6];
    float* out = (float*)d_out;

    const int n = in_sizes[0] / 256;
    const int E = in_sizes[1] / 2;
    const int* src = ei;
    const int* dst = ei + E;
    const int Epad = E + 16 * n + 64;  // padded col capacity (+margin)

    char* ws = (char*)d_ws;
    size_t off = 0;
    auto alloc = [&](size_t bytes) -> void* {
        off = (off + 255) & ~(size_t)255;
        void* p = (void*)(ws + off);
        off += bytes;
        return p;
    };
    size_t bufBytes = (size_t)n * 128 * sizeof(float);            // 8 chunks x n x 16
    size_t mirBytes = (size_t)(n + 1) * 128 * sizeof(__half);     // 8 chunks x (n+1) x 16
    float* bufA   = (float*)alloc(bufBytes);
    float* bufB   = (float*)alloc(bufBytes);
    float* bufC   = (float*)alloc(bufBytes);
    float* mirA   = (float*)alloc(mirBytes);
    float* mirB   = (float*)alloc(mirBytes);
    int*   col    = (int*)alloc((size_t)Epad * sizeof(int));
    int*   degs   = (int*)alloc((size_t)n * sizeof(int));
    int*   cntd   = (int*)alloc((size_t)n * sizeof(int));
    int*   rowptr = (int*)alloc((size_t)(n + 1) * sizeof(int));
    int*   cursor = (int*)alloc((size_t)n * sizeof(int));
    int*   bsum   = (int*)alloc(1024 * sizeof(int));
    float* dinv   = (float*)alloc((size_t)n * sizeof(float));

    (void)hipMemsetAsync(degs, 0, (size_t)n * sizeof(int), stream);
    (void)hipMemsetAsync(cntd, 0, (size_t)n * sizeof(int), stream);

    // ---- CSR build (by dst), padded to x16 rows, col-only records ----
    hist_kernel<<<2048, 256, 0, stream>>>(src, dst, degs, cntd, E);
    dinv_kernel<<<(n + 255) / 256, 256, 0, stream>>>(degs, dinv, n);
    int nchunk = (n + SCAN_CHUNK - 1) / SCAN_CHUNK;
    scan_chunk_sum<<<nchunk, SCAN_BLOCK, 0, stream>>>(cntd, bsum, n);
    scan_bsum<<<1, 64, 0, stream>>>(bsum, nchunk);
    scan_write<<<nchunk, SCAN_BLOCK, 0, stream>>>(cntd, bsum, rowptr, cursor, n);
    fillcol_kernel<<<2048, 256, 0, stream>>>(col, Epad, n);
    scatter_kernel<<<4096, 256, 0, stream>>>(src, dst, cursor, col, E);

    // ---- h = relu(x @ W1 + b1) (chunk-major) + pre-scaled fp16 mirror ----
    gemm1_kernel<<<(n + G1_ROWS - 1) / G1_ROWS, 128, 0, stream>>>(x, W1, b1, bufA, n);
    dim3 mgrid(1024, 8);
    mirror_kernel<<<mgrid, 256, 0, stream>>>((const float4*)bufA, (fx2*)mirA, dinv, n);
    pad_kernel<<<1, 128, 0, stream>>>(mirA, mirB, n);

    // ---- 2 BernConv layers ----
    int pgrid = ((n + 31) / 32) * 8;  // 32 nodes per block x 8 feature chunks
    float* A  = bufA;
    float* B  = bufB;
    float* C  = bufC;
    float* mA = mirA;
    float* mB = mirB;
    for (int l = 0; l < 2; ++l) {
        // k=0,1 fused: tx1 = 0.5x - agg(x) -> B (+mirror mB); OUT = c0*x + c1*tx1
        prop_kernel<<<pgrid, 256, 0, stream>>>(A, mA, A, C, B, mB, rowptr, col, dinv,
                                               coeffs, l * 11 + 0, 0, n);
        float* t0 = A;  float* m0 = mA;
        float* t1 = B;  float* m1 = mB;
        for (int k = 2; k <= 9; ++k) {
            // gather from t1's mirror m1; tx2 overwrites t0 (+mirror m0)
            prop_kernel<<<pgrid, 256, 0, stream>>>(t1, m1, t0, C, nullptr, m0, rowptr,
                                                   col, dinv, coeffs, l * 11 + k, 1, n);
            float* tf = t0; t0 = t1; t1 = tf;
            float* tm = m0; m0 = m1; m1 = tm;
        }
        // k=10: fold last term + ReLU -> t0 (+mirror m0 if another layer follows)
        prop_kernel<<<pgrid, 256, 0, stream>>>(t1, m1, t0, C, nullptr,
                                               (l == 0) ? m0 : nullptr, rowptr, col,
                                               dinv, coeffs, l * 11 + 10, 2, n);
        A = t0; mA = m0;   // next layer input
        B = t1; mB = m1;
    }

    // ---- out = h @ W2 + b2 ----
    gemm2_kernel<<<(n + G2_ROWS - 1) / G2_ROWS, 64, 0, stream>>>(A, W2, b2, out, n);
}

// Round 11
// 3529.705 us; speedup vs baseline: 2.5916x; 1.7831x over previous
//
#include <hip/hip_runtime.h>
#include <hip/hip_fp16.h>

// ---------------------------------------------------------------------------
// BernNet forward: x@W1+b1 -> relu -> 2x BernConv(K=10) -> h@W2+b2
// R11 = R5's proven whole-row gather structure (one wave/node, 256B coalesced
// fp16 mirror rows, 4-deep unroll) + the chunking arc's validated wins:
// mirror stores u = dinv[v]*T[v] (pre-scaled) so CSR is a bare 4B col array
// (no weight shuffles, half the edge stream, 4B scatter stores); padding
// gather slots index dummy zero row n. R7-R10's feature-chunked layout was
// request-rate bound (32B rows = half-sector reads, 8x request inflation);
// whole 256B rows are the efficient shape. f32 h-domain recurrence masters.
// Gather trip counts are wave-uniform (divergent __shfl undefined on CDNA).
// ---------------------------------------------------------------------------

#define SCAN_BLOCK 256
#define SCAN_ITEMS 4
#define SCAN_CHUNK 1024

typedef float fx2 __attribute__((ext_vector_type(2)));

union f2h4 { fx2 f2; __half2 h2[2]; };

__global__ __launch_bounds__(256) void hist_kernel(const int* __restrict__ src,
                                                   const int* __restrict__ dst,
                                                   int* __restrict__ deg_src,
                                                   int* __restrict__ cnt_dst, int E) {
    int stride = gridDim.x * blockDim.x;
    for (int e = blockIdx.x * blockDim.x + threadIdx.x; e < E; e += stride) {
        atomicAdd(&deg_src[src[e]], 1);
        atomicAdd(&cnt_dst[dst[e]], 1);
    }
}

__global__ __launch_bounds__(256) void dinv_kernel(const int* __restrict__ deg,
                                                   float* __restrict__ dinv, int n) {
    int i = blockIdx.x * blockDim.x + threadIdx.x;
    if (i < n) {
        int d = deg[i];
        dinv[i] = d > 0 ? rsqrtf((float)d) : 0.f;
    }
}

__global__ __launch_bounds__(SCAN_BLOCK) void scan_chunk_sum(const int* __restrict__ cnt,
                                                             int* __restrict__ bsum, int n) {
    __shared__ int sdata[SCAN_BLOCK];
    int tid = threadIdx.x;
    int base = blockIdx.x * SCAN_CHUNK + tid * SCAN_ITEMS;
    int s = 0;
    for (int i = 0; i < SCAN_ITEMS; ++i) {
        int idx = base + i;
        if (idx < n) s += cnt[idx];
    }
    sdata[tid] = s;
    __syncthreads();
    for (int off = SCAN_BLOCK / 2; off > 0; off >>= 1) {
        if (tid < off) sdata[tid] += sdata[tid + off];
        __syncthreads();
    }
    if (tid == 0) bsum[blockIdx.x] = sdata[0];
}

__global__ void scan_bsum(int* __restrict__ bsum, int nb) {
    if (threadIdx.x == 0 && blockIdx.x == 0) {
        int run = 0;
        for (int i = 0; i < nb; ++i) {
            int v = bsum[i];
            bsum[i] = run;
            run += v;
        }
    }
}

__global__ __launch_bounds__(SCAN_BLOCK) void scan_write(const int* __restrict__ cnt,
                                                         const int* __restrict__ bsum,
                                                         int* __restrict__ rowptr,
                                                         int* __restrict__ cursor,
                                                         int n, int total) {
    __shared__ int sdata[SCAN_BLOCK];
    int tid = threadIdx.x;
    int base = blockIdx.x * SCAN_CHUNK + tid * SCAN_ITEMS;
    int vals[SCAN_ITEMS];
    int s = 0;
    for (int i = 0; i < SCAN_ITEMS; ++i) {
        int idx = base + i;
        vals[i] = (idx < n) ? cnt[idx] : 0;
        s += vals[i];
    }
    sdata[tid] = s;
    __syncthreads();
    for (int off = 1; off < SCAN_BLOCK; off <<= 1) {
        int add = (tid >= off) ? sdata[tid - off] : 0;
        __syncthreads();
        sdata[tid] += add;
        __syncthreads();
    }
    int run = bsum[blockIdx.x] + sdata[tid] - s;
    for (int i = 0; i < SCAN_ITEMS; ++i) {
        int idx = base + i;
        if (idx < n) {
            rowptr[idx] = run;
            cursor[idx] = run;
        }
        run += vals[i];
    }
    if (blockIdx.x == 0 && tid == 0) rowptr[n] = total;
}

// bare 4B record per edge: source index only (weights folded into mirror)
__global__ __launch_bounds__(256) void scatter_kernel(const int* __restrict__ src,
                                                      const int* __restrict__ dst,
                                                      int* __restrict__ cursor,
                                                      int* __restrict__ col, int E) {
    int stride = gridDim.x * blockDim.x;
    for (int e = blockIdx.x * blockDim.x + threadIdx.x; e < E; e += stride) {
        int d = dst[e];
        int p = atomicAdd(&cursor[d], 1);
        col[p] = src[e];
    }
}

// f32 row-major -> pre-scaled fp16 mirror (u = dinv[v] * h[v]); 256B rows
__global__ __launch_bounds__(256) void mirror_kernel(const float4* __restrict__ src,
                                                     fx2* __restrict__ dst,
                                                     const float* __restrict__ dinv,
                                                     int n4) {
    int stride = gridDim.x * blockDim.x;
    for (int i = blockIdx.x * blockDim.x + threadIdx.x; i < n4; i += stride) {
        int v = i >> 5;  // 32 float4 per 128-feature row
        float dv = dinv[v];
        float4 x = src[i];
        f2h4 u;
        u.h2[0] = __floats2half2_rn(x.x * dv, x.y * dv);
        u.h2[1] = __floats2half2_rn(x.z * dv, x.w * dv);
        dst[i] = u.f2;
    }
}

// zero the dummy gather row (index n) of both mirrors (64 dwords each)
__global__ void pad_kernel(float* __restrict__ mA, float* __restrict__ mB, int n) {
    int t = threadIdx.x;  // 128 threads
    if (t < 64) mA[(size_t)n * 64 + t] = 0.f;
    else mB[(size_t)n * 64 + (t - 64)] = 0.f;
}

// -------------------- GEMM1: h = relu(x @ W1 + b1), K=256, cols=128 --------
#define G1_ROWS 16
__global__ __launch_bounds__(128) void gemm1_kernel(const float* __restrict__ X,
                                                    const float* __restrict__ W,
                                                    const float* __restrict__ b,
                                                    float* __restrict__ H, int n) {
    __shared__ float xt[G1_ROWS][256];
    int j = threadIdx.x;
    int r0 = blockIdx.x * G1_ROWS;
    for (int i = threadIdx.x; i < G1_ROWS * 256; i += 128) {
        int r = i >> 8, k = i & 255;
        int row = r0 + r;
        xt[r][k] = (row < n) ? X[(size_t)row * 256 + k] : 0.f;
    }
    __syncthreads();
    float acc[G1_ROWS];
#pragma unroll
    for (int r = 0; r < G1_ROWS; ++r) acc[r] = 0.f;
    for (int k = 0; k < 256; ++k) {
        float wk = W[k * 128 + j];
#pragma unroll
        for (int r = 0; r < G1_ROWS; ++r) acc[r] += xt[r][k] * wk;
    }
    float bj = b[j];
    for (int r = 0; r < G1_ROWS; ++r) {
        int row = r0 + r;
        if (row < n) H[(size_t)row * 128 + j] = fmaxf(acc[r] + bj, 0.f);
    }
}

// -------------------- GEMM2: out = h @ W2 + b2, K=128, cols=64 -------------
#define G2_ROWS 32
__global__ __launch_bounds__(64) void gemm2_kernel(const float* __restrict__ H,
                                                   const float* __restrict__ W,
                                                   const float* __restrict__ b,
                                                   float* __restrict__ O, int n) {
    __shared__ float xt[G2_ROWS][128];
    int j = threadIdx.x;
    int r0 = blockIdx.x * G2_ROWS;
    for (int i = threadIdx.x; i < G2_ROWS * 128; i += 64) {
        int r = i >> 7, k = i & 127;
        int row = r0 + r;
        xt[r][k] = (row < n) ? H[(size_t)row * 128 + k] : 0.f;
    }
    __syncthreads();
    float acc[G2_ROWS];
#pragma unroll
    for (int r = 0; r < G2_ROWS; ++r) acc[r] = 0.f;
    for (int k = 0; k < 128; ++k) {
        float wk = W[k * 64 + j];
#pragma unroll
        for (int r = 0; r < G2_ROWS; ++r) acc[r] += xt[r][k] * wk;
    }
    float bj = b[j];
    for (int r = 0; r < G2_ROWS; ++r) {
        int row = r0 + r;
        if (row < n) O[(size_t)row * 64 + j] = acc[r] + bj;
    }
}

// -------------------- Fused Chebyshev propagation step ---------------------
// One wave per node. Two 32-lane halves each gather a different edge's mirror
// row (256B: lane q loads float2 = 4 fp16 features); 4 independent row loads
// in flight per half. Trip count is wave-uniform: iters = ceil(m/2) for BOTH
// halves; padding slots (lane >= m) hold dummy row n (zeros, L1-hot).
// acc = sum_e u[col[e]]; agg = -0.5*dinv[v]*acc. Mirror rows hold
// u = dinv[v]*value; MH (may be null) receives the mirror of the value
// written this step. f32 masters stay in h-domain.
// mode 0: tx1 = 0.5x - agg -> TX1 (+MH); OUT = c0*x + c1*tx1
// mode 1: tx2 = x - 2*agg - t0; OUT += ck*tx2; T0 <- tx2 (+MH)
// mode 2: T0 <- relu(OUT + ck*tx2) (+MH)   (layer end)
__global__ __launch_bounds__(256) void prop_kernel(const float* __restrict__ XF,
                                                   const fx2* __restrict__ XH,
                                                   float* __restrict__ T0,
                                                   float* __restrict__ OUT,
                                                   float* __restrict__ TX1,
                                                   fx2* __restrict__ MH,
                                                   const int* __restrict__ rowptr,
                                                   const int* __restrict__ col,
                                                   const float* __restrict__ dinv,
                                                   const float* __restrict__ coeffs,
                                                   int cidx, int mode, int n) {
    int wave = (blockIdx.x * blockDim.x + threadIdx.x) >> 6;
    if (wave >= n) return;
    int lane = threadIdx.x & 63;
    int half = lane >> 5;
    int q = lane & 31;
    int v = wave;
    int start = rowptr[v];
    int end = rowptr[v + 1];

    float4 a0 = {0, 0, 0, 0}, a1 = {0, 0, 0, 0}, a2 = {0, 0, 0, 0}, a3 = {0, 0, 0, 0};

    for (int e0 = start; e0 < end; e0 += 64) {
        int m = end - e0;
        if (m > 64) m = 64;
        int sE = n;  // dummy zero row for padding slots
        if (lane < m) sE = col[e0 + lane];
        // WAVE-UNIFORM trip count: both halves run ceil(m/2) iterations.
        // For odd m, half 1's last shuffle reads lane m (holds sE = n).
        int iters = (m + 1) >> 1;
        int t = 0;
        for (; t + 4 <= iters; t += 4) {
            int j0 = 2 * t + half;
            int s0 = __shfl(sE, j0);
            int s1 = __shfl(sE, j0 + 2);
            int s2 = __shfl(sE, j0 + 4);
            int s3 = __shfl(sE, j0 + 6);
            f2h4 c0, c1, c2, c3;
            c0.f2 = XH[(size_t)s0 * 32 + q];
            c1.f2 = XH[(size_t)s1 * 32 + q];
            c2.f2 = XH[(size_t)s2 * 32 + q];
            c3.f2 = XH[(size_t)s3 * 32 + q];
            float2 lo, hi;
            lo = __half22float2(c0.h2[0]); hi = __half22float2(c0.h2[1]);
            a0.x += lo.x; a0.y += lo.y; a0.z += hi.x; a0.w += hi.y;
            lo = __half22float2(c1.h2[0]); hi = __half22float2(c1.h2[1]);
            a1.x += lo.x; a1.y += lo.y; a1.z += hi.x; a1.w += hi.y;
            lo = __half22float2(c2.h2[0]); hi = __half22float2(c2.h2[1]);
            a2.x += lo.x; a2.y += lo.y; a2.z += hi.x; a2.w += hi.y;
            lo = __half22float2(c3.h2[0]); hi = __half22float2(c3.h2[1]);
            a3.x += lo.x; a3.y += lo.y; a3.z += hi.x; a3.w += hi.y;
        }
        for (; t < iters; ++t) {
            int j0 = 2 * t + half;
            int s0 = __shfl(sE, j0);
            f2h4 c0;
            c0.f2 = XH[(size_t)s0 * 32 + q];
            float2 lo = __half22float2(c0.h2[0]);
            float2 hi = __half22float2(c0.h2[1]);
            a0.x += lo.x; a0.y += lo.y; a0.z += hi.x; a0.w += hi.y;
        }
    }
    float4 acc;
    acc.x = (a0.x + a1.x) + (a2.x + a3.x);
    acc.y = (a0.y + a1.y) + (a2.y + a3.y);
    acc.z = (a0.z + a1.z) + (a2.z + a3.z);
    acc.w = (a0.w + a1.w) + (a2.w + a3.w);
    acc.x += __shfl_xor(acc.x, 32);
    acc.y += __shfl_xor(acc.y, 32);
    acc.z += __shfl_xor(acc.z, 32);
    acc.w += __shfl_xor(acc.w, 32);

    if (half) return;  // lanes 0..31 run the epilogue (32 x float4 = full row)

    float dv = dinv[v];
    float sw = -0.5f * dv;
    float gx = sw * acc.x;
    float gy = sw * acc.y;
    float gz = sw * acc.z;
    float gw = sw * acc.w;

    size_t idx = (size_t)v * 32 + q;
    const float4* __restrict__ X4 = reinterpret_cast<const float4*>(XF);
    float4 self = X4[idx];
    float4 wr;  // value written to the T-buffer this step (mirrored to MH)

    if (mode == 0) {
        float c0 = coeffs[cidx];
        float c1 = coeffs[cidx + 1];
        wr.x = 0.5f * self.x - gx;
        wr.y = 0.5f * self.y - gy;
        wr.z = 0.5f * self.z - gz;
        wr.w = 0.5f * self.w - gw;
        reinterpret_cast<float4*>(TX1)[idx] = wr;
        float4 o;
        o.x = c0 * self.x + c1 * wr.x;
        o.y = c0 * self.y + c1 * wr.y;
        o.z = c0 * self.z + c1 * wr.z;
        o.w = c0 * self.w + c1 * wr.w;
        reinterpret_cast<float4*>(OUT)[idx] = o;
    } else {
        float ck = coeffs[cidx];
        float4 t0v = reinterpret_cast<const float4*>(T0)[idx];
        float4 t2;
        t2.x = self.x - 2.f * gx - t0v.x;
        t2.y = self.y - 2.f * gy - t0v.y;
        t2.z = self.z - 2.f * gz - t0v.z;
        t2.w = self.w - 2.f * gw - t0v.w;
        float4 o = reinterpret_cast<float4*>(OUT)[idx];
        o.x += ck * t2.x;
        o.y += ck * t2.y;
        o.z += ck * t2.z;
        o.w += ck * t2.w;
        if (mode == 1) {
            wr = t2;
            reinterpret_cast<float4*>(T0)[idx] = wr;
            reinterpret_cast<float4*>(OUT)[idx] = o;
        } else {
            wr.x = fmaxf(o.x, 0.f);
            wr.y = fmaxf(o.y, 0.f);
            wr.z = fmaxf(o.z, 0.f);
            wr.w = fmaxf(o.w, 0.f);
            reinterpret_cast<float4*>(T0)[idx] = wr;
        }
    }
    if (MH) {
        f2h4 u;
        u.h2[0] = __floats2half2_rn(wr.x * dv, wr.y * dv);
        u.h2[1] = __floats2half2_rn(wr.z * dv, wr.w * dv);
        MH[idx] = u.f2;
    }
}

// ---------------------------------------------------------------------------

extern "C" void kernel_launch(void* const* d_in, const int* in_sizes, int n_in,
                              void* d_out, int out_size, void* d_ws, size_t ws_size,
                              hipStream_t stream) {
    const float* x      = (const float*)d_in[0];
    const int*   ei     = (const int*)d_in[1];
    const float* W1     = (const float*)d_in[2];
    const float* b1     = (const float*)d_in[3];
    const float* coeffs = (const float*)d_in[4];
    const float* W2     = (const float*)d_in[5];
    const float* b2     = (const float*)d_in[6];
    float* out = (float*)d_out;

    const int n = in_sizes[0] / 256;
    const int E = in_sizes[1] / 2;
    const int* src = ei;
    const int* dst = ei + E;

    char* ws = (char*)d_ws;
    size_t off = 0;
    auto alloc = [&](size_t bytes) -> void* {
        off = (off + 255) & ~(size_t)255;
        void* p = (void*)(ws + off);
        off += bytes;
        return p;
    };
    size_t bufBytes = (size_t)n * 128 * sizeof(float);
    size_t mirBytes = (size_t)(n + 1) * 128 * sizeof(__half);  // +1 dummy zero row
    float* bufA   = (float*)alloc(bufBytes);
    float* bufB   = (float*)alloc(bufBytes);
    float* bufC   = (float*)alloc(bufBytes);
    fx2*   mirA   = (fx2*)alloc(mirBytes);
    fx2*   mirB   = (fx2*)alloc(mirBytes);
    int*   col    = (int*)alloc((size_t)E * sizeof(int));
    int*   degs   = (int*)alloc((size_t)n * sizeof(int));
    int*   cntd   = (int*)alloc((size_t)n * sizeof(int));
    int*   rowptr = (int*)alloc((size_t)(n + 1) * sizeof(int));
    int*   cursor = (int*)alloc((size_t)n * sizeof(int));
    int*   bsum   = (int*)alloc(1024 * sizeof(int));
    float* dinv   = (float*)alloc((size_t)n * sizeof(float));

    (void)hipMemsetAsync(degs, 0, (size_t)n * sizeof(int), stream);
    (void)hipMemsetAsync(cntd, 0, (size_t)n * sizeof(int), stream);

    // ---- CSR build (by dst), col-only records ----
    hist_kernel<<<2048, 256, 0, stream>>>(src, dst, degs, cntd, E);
    dinv_kernel<<<(n + 255) / 256, 256, 0, stream>>>(degs, dinv, n);
    int nchunk = (n + SCAN_CHUNK - 1) / SCAN_CHUNK;
    scan_chunk_sum<<<nchunk, SCAN_BLOCK, 0, stream>>>(cntd, bsum, n);
    scan_bsum<<<1, 64, 0, stream>>>(bsum, nchunk);
    scan_write<<<nchunk, SCAN_BLOCK, 0, stream>>>(cntd, bsum, rowptr, cursor, n, E);
    scatter_kernel<<<4096, 256, 0, stream>>>(src, dst, cursor, col, E);

    // ---- h = relu(x @ W1 + b1) + pre-scaled fp16 mirror ----
    gemm1_kernel<<<(n + G1_ROWS - 1) / G1_ROWS, 128, 0, stream>>>(x, W1, b1, bufA, n);
    mirror_kernel<<<2048, 256, 0, stream>>>((const float4*)bufA, mirA, dinv, n * 32);
    pad_kernel<<<1, 128, 0, stream>>>((float*)mirA, (float*)mirB, n);

    // ---- 2 BernConv layers ----
    int pgrid = (n + 3) / 4;  // 4 waves (nodes) per 256-thread block
    float* A  = bufA;
    float* B  = bufB;
    float* C  = bufC;
    fx2*   mA = mirA;
    fx2*   mB = mirB;
    for (int l = 0; l < 2; ++l) {
        // k=0,1 fused: tx1 = 0.5x - agg(x) -> B (+mirror mB); OUT = c0*x + c1*tx1
        prop_kernel<<<pgrid, 256, 0, stream>>>(A, mA, A, C, B, mB, rowptr, col, dinv,
                                               coeffs, l * 11 + 0, 0, n);
        float* t0 = A;  fx2* m0 = mA;
        float* t1 = B;  fx2* m1 = mB;
        for (int k = 2; k <= 9; ++k) {
            // gather from t1's mirror m1; tx2 overwrites t0 (+mirror m0)
            prop_kernel<<<pgrid, 256, 0, stream>>>(t1, m1, t0, C, nullptr, m0, rowptr,
                                                   col, dinv, coeffs, l * 11 + k, 1, n);
            float* tf = t0; t0 = t1; t1 = tf;
            fx2* tm = m0; m0 = m1; m1 = tm;
        }
        // k=10: fold last term + ReLU -> t0 (+mirror m0 if another layer follows)
        prop_kernel<<<pgrid, 256, 0, stream>>>(t1, m1, t0, C, nullptr,
                                               (l == 0) ? m0 : nullptr, rowptr, col,
                                               dinv, coeffs, l * 11 + 10, 2, n);
        A = t0; mA = m0;   // next layer input
        B = t1; mB = m1;
    }

    // ---- out = h @ W2 + b2 ----
    gemm2_kernel<<<(n + G2_ROWS - 1) / G2_ROWS, 64, 0, stream>>>(A, W2, b2, out, n);
}